// Round 13
// baseline (631.384 us; speedup 1.0000x reference)
//
#include <hip/hip_runtime.h>

// ---------- problem constants ----------
#define BB   4096
#define IN_  256
#define NN   128
#define NG   512
#define WS_  131072     // IN*NG
#define PER  131584     // WS_+NG
#define TP   263168     // 2*PER

typedef __attribute__((ext_vector_type(8))) short short8;
typedef __attribute__((ext_vector_type(4))) float f32x4;

__device__ __forceinline__ unsigned short f2bf(float f){
  unsigned u = __float_as_uint(f);
  return (unsigned short)((u + 0x7fffu + ((u >> 16) & 1u)) >> 16);
}

// sum over each 16-lane row via DPP (VALU pipe)
__device__ __forceinline__ float rowred16(float s){
  s += __int_as_float(__builtin_amdgcn_update_dpp(0, __float_as_int(s), 0xB1,  0xF, 0xF, true));
  s += __int_as_float(__builtin_amdgcn_update_dpp(0, __float_as_int(s), 0x4E,  0xF, 0xF, true));
  s += __int_as_float(__builtin_amdgcn_update_dpp(0, __float_as_int(s), 0x124, 0xF, 0xF, true));
  s += __int_as_float(__builtin_amdgcn_update_dpp(0, __float_as_int(s), 0x128, 0xF, 0xF, true));
  return s;
}

// ---------- 1. f32 -> bf16 convert: x only ----------
__global__ void k_convert(const float* __restrict__ x, unsigned short* __restrict__ xb){
  size_t i = ((size_t)blockIdx.x*256 + threadIdx.x)*4;
  float4 v = *(const float4*)(x + i);
  ushort4 o;
  o.x = f2bf(v.x); o.y = f2bf(v.y); o.z = f2bf(v.z); o.w = f2bf(v.w);
  *(ushort4*)(xb + i) = o;
}

// ---------- 2. hypernet MLP + gw matvec (merged) ----------
__global__ __launch_bounds__(512)
void k_gw(const float* __restrict__ ctx,
          const float* __restrict__ h1w, const float* __restrict__ h1b,
          const float* __restrict__ h2w, const float* __restrict__ h2b,
          const float* __restrict__ h3w, const float* __restrict__ h3b,
          unsigned short* __restrict__ Wg_bf, float* __restrict__ bg){
  __shared__ float s1[32];
  __shared__ float hv2[64];
  const int t = threadIdx.x;
  if (t < 32){
    float a = h1b[t];
    #pragma unroll 8
    for (int i = 0; i < 64; ++i) a += ctx[i]*h1w[t*64+i];
    s1[t] = fmaxf(a, 0.f);
  }
  __syncthreads();
  if (t < 64){
    float a = h2b[t];
    #pragma unroll 8
    for (int i = 0; i < 32; ++i) a += s1[i]*h2w[t*32+i];
    hv2[t] = fmaxf(a, 0.f);
  }
  __syncthreads();

  const int r = blockIdx.x*64 + (t >> 3);
  const int q = t & 7;
  const float4* row = (const float4*)(h3w + (size_t)r*64);
  float4 v0 = row[q*2], v1 = row[q*2+1];
  float4 h0 = *(const float4*)(hv2 + q*8), h1 = *(const float4*)(hv2 + q*8 + 4);
  float a = v0.x*h0.x + v0.y*h0.y + v0.z*h0.z + v0.w*h0.w
          + v1.x*h1.x + v1.y*h1.y + v1.z*h1.z + v1.w*h1.w;
  a += __shfl_xor(a, 1);
  a += __shfl_xor(a, 2);
  a += __shfl_xor(a, 4);
  if (q == 0){
    a += h3b[r];
    if (r < WS_)          Wg_bf[r] = f2bf(a);
    else if (r < PER)     bg[r - WS_] = a;
    else if (r < PER+WS_) Wg_bf[WS_ + (r - PER)] = f2bf(a);
    else                  bg[512 + (r - (PER+WS_))] = a;
  }
}

// ---------- 4. gates GEMM: G_T[m][b] = sigmoid(Wg[m]·x[b] + bg[m]) ----------
__global__ __launch_bounds__(512, 1)
void k_gates(const unsigned short* __restrict__ Wg_bf,
             const unsigned short* __restrict__ x_bf,
             const float* __restrict__ bg,
             float* __restrict__ GT){
  __shared__ __align__(16) unsigned short As[128*64];
  __shared__ __align__(16) unsigned short Bs[256*64];
  const int tid  = threadIdx.x;
  const int lane = tid & 63;
  const int wid  = tid >> 6;
  const int wm = wid >> 2, wn = wid & 3;
  const int lrow = lane & 15, lk = lane >> 4;
  const int m0 = blockIdx.x*128;
  const int b0 = blockIdx.y*256;

  f32x4 zero = {0.f,0.f,0.f,0.f};
  f32x4 acc[4][4];
  #pragma unroll
  for (int i=0;i<4;++i)
    #pragma unroll
    for (int j=0;j<4;++j) acc[i][j] = zero;

  for (int kt = 0; kt < 256/64; ++kt){
    __syncthreads();
    #pragma unroll
    for (int i = 0; i < 2; ++i){
      int c = tid + i*512;
      int row = c >> 3, k8 = c & 7;
      uint4 v = *(const uint4*)(Wg_bf + (size_t)(m0+row)*256 + kt*64 + k8*8);
      int idx = (row*64 + k8*8) ^ ((row & 7) << 3);
      *(uint4*)(&As[idx]) = v;
    }
    #pragma unroll
    for (int i = 0; i < 4; ++i){
      int c = tid + i*512;
      int row = c >> 3, k8 = c & 7;
      uint4 v = *(const uint4*)(x_bf + (size_t)(b0+row)*256 + kt*64 + k8*8);
      int idx = (row*64 + k8*8) ^ ((row & 7) << 3);
      *(uint4*)(&Bs[idx]) = v;
    }
    __syncthreads();
    #pragma unroll
    for (int kk = 0; kk < 2; ++kk){
      short8 a[4], b[4];
      #pragma unroll
      for (int fm = 0; fm < 4; ++fm){
        int m = wm*64 + fm*16 + lrow;
        int idx = (m*64 + kk*32 + lk*8) ^ ((m & 7) << 3);
        a[fm] = *(const short8*)(&As[idx]);
      }
      #pragma unroll
      for (int fn = 0; fn < 4; ++fn){
        int r = wn*64 + fn*16 + lrow;
        int idx = (r*64 + kk*32 + lk*8) ^ ((r & 7) << 3);
        b[fn] = *(const short8*)(&Bs[idx]);
      }
      #pragma unroll
      for (int fm = 0; fm < 4; ++fm)
        #pragma unroll
        for (int fn = 0; fn < 4; ++fn)
          acc[fm][fn] = __builtin_amdgcn_mfma_f32_16x16x32_bf16(a[fm], b[fn], acc[fm][fn], 0, 0, 0);
    }
  }
  #pragma unroll
  for (int fm = 0; fm < 4; ++fm){
    float4 bgv = *(const float4*)(bg + m0 + wm*64 + fm*16 + lk*4);
    float bga[4] = {bgv.x, bgv.y, bgv.z, bgv.w};
    #pragma unroll
    for (int reg = 0; reg < 4; ++reg){
      int m = m0 + wm*64 + fm*16 + lk*4 + reg;
      #pragma unroll
      for (int fn = 0; fn < 4; ++fn){
        int b = b0 + wn*64 + fn*16 + lrow;
        float z = acc[fm][fn][reg] + bga[reg];
        GT[(size_t)m*4096 + b] = 1.f/(1.f + __expf(-z));
      }
    }
  }
}

// ---------- 5/6. fused DANN layer (barrier-free; CORRECT launch bounds) ----------
// Same structure as R12: LDS = resident Wb only (64 KB, staged once);
// A-frags stream global->VGPR double-buffered; no main-loop barriers.
// FIX vs R12: __launch_bounds__(1024, 4) -> 16 waves/CU (1 block), VGPR cap
// 128 (R12's (1024,1) let the allocator target 2 blocks/CU at 64 VGPR ->
// full scratch spill, 135 MB scratch writes, 954 MB fetch). Register need
// ~111: acc 32 + areg 32 + gv/bbv/wsv 16 + b 16 + addr ~15.
// kt loop explicitly unrolled so areg indices are compile-time (rule #20).
template<int KIN, int LAYER>
__global__ __launch_bounds__(1024, 4)
void k_layer(const unsigned short* __restrict__ Abf,  // (4096, KIN) bf16
             const float* __restrict__ Wf32,          // (32768, KIN) f32
             const float* __restrict__ bb,
             const float* __restrict__ Ws,
             const float* __restrict__ GT,            // 1024 x 4096
             float* __restrict__ partg){              // [4][128][4096] f32
  constexpr int NT   = KIN/64;                   // 4 / 2
  constexpr int SC   = (LAYER==0) ? 128 : 256;   // resident Wb cols
  constexpr int WN   = SC/64;                    // 2 / 4
  constexpr int BTR  = (LAYER==0) ? 256 : 128;   // rows per bt
  constexpr int NBT  = 16;
  constexpr int NPH  = NBT*NT;
  constexpr unsigned KTB = SC*64*2;              // bytes per Wb kt-tile
  __shared__ __align__(16) unsigned short lds[SC*64*NT];   // 64 KB both layers

  const int tid  = threadIdx.x;                  // 0..1023
  const int lane = tid & 63;
  const int wid  = tid >> 6;                     // 0..15
  const int wn   = wid % WN, wm = wid / WN;
  const int lrow = lane & 15, lk = lane >> 4;

  const int id      = blockIdx.x;                // 0..255
  const int n       = id >> 1;
  const int sub     = id & 1;
  const int kgrp    = (LAYER==0) ? sub*2 + wn : wn;
  const int abase   = (LAYER==0) ? 0 : sub*2048;
  const int colbase = n*256 + ((LAYER==0) ? sub*128 : 0);

  f32x4 zero = {0.f,0.f,0.f,0.f};
  f32x4 acc[2][4];
  #pragma unroll
  for (int i=0;i<2;++i)
    #pragma unroll
    for (int jj=0;jj<4;++jj) acc[i][jj] = zero;

  // ---- prologue: Wb f32 -> bf16 swizzled LDS staging (4096 16B-chunks) ----
  {
    constexpr int CHPR = KIN/8;                  // 16B-chunks per Wb row
    float4 va[4], vb[4];
    #pragma unroll
    for (int j = 0; j < 4; ++j){
      int c = j*1024 + tid;
      int r = c / CHPR, q = c % CHPR;
      const float4* s = (const float4*)(Wf32 + (size_t)(colbase + r)*KIN + q*8);
      va[j] = s[0]; vb[j] = s[1];
    }
    #pragma unroll
    for (int j = 0; j < 4; ++j){
      int c = j*1024 + tid;
      int r = c / CHPR, q = c % CHPR;
      int kt = q >> 3, k8 = q & 7;
      short8 p;
      p[0] = (short)f2bf(va[j].x); p[1] = (short)f2bf(va[j].y);
      p[2] = (short)f2bf(va[j].z); p[3] = (short)f2bf(va[j].w);
      p[4] = (short)f2bf(vb[j].x); p[5] = (short)f2bf(vb[j].y);
      p[6] = (short)f2bf(vb[j].z); p[7] = (short)f2bf(vb[j].w);
      int dst = kt*SC*64 + ((r*64 + k8*8) ^ ((r&7)<<3));
      *(short8*)(&lds[dst]) = p;
    }
  }

  // per-lane A base: rows (abase + wm*32 + fm*16 + lrow), k-chunk lk*8
  const unsigned short* abp = Abf + (size_t)(abase + wm*32 + lrow)*KIN + lk*8;

  // A-frag loads (global -> VGPR, 4 x dwordx4), static buffer indices
  short8 areg[2][2][2];                          // [buf][kk][fm]
  #define ALOAD(BUF, BT, KT)                                                   \
    _Pragma("unroll")                                                          \
    for (int kk_ = 0; kk_ < 2; ++kk_)                                          \
      _Pragma("unroll")                                                        \
      for (int fm_ = 0; fm_ < 2; ++fm_)                                        \
        areg[BUF][kk_][fm_] = *(const short8*)(abp +                           \
            (size_t)((BT)*BTR + fm_*16)*KIN + (KT)*64 + kk_*32);

  ALOAD(0, 0, 0)
  __syncthreads();                               // publish Wb LDS (once)

  // block-constant epilogue params
  float bbv[4], wsv[4];
  #pragma unroll
  for (int fn = 0; fn < 4; ++fn){
    int cloc = ((LAYER==0) ? sub*128 : 0) + wn*64 + fn*16 + lrow;
    bbv[fn] = bb[n*256 + cloc];
    wsv[fn] = Ws[n*256 + cloc];
  }
  const float* gtrow = GT + (size_t)(LAYER*512 + n*4 + kgrp)*4096 + abase;
  float* prow = partg + (size_t)kgrp*524288 + (size_t)n*4096 + abase;

  unsigned boff[4];
  #pragma unroll
  for (int fn = 0; fn < 4; ++fn){
    int r = wn*64 + fn*16 + lrow;
    boff[fn] = 2u*((unsigned)((r*64 + lk*8) ^ ((r & 7) << 3)));
  }
  const char* ldsc = (const char*)lds;

  #pragma unroll 1
  for (int bt = 0; bt < NBT; ++bt){
    float4 gv[2];
    #pragma unroll
    for (int kt = 0; kt < NT; ++kt){
      const int ph = bt*NT + kt;
      const int cb = kt & 1;                     // compile-time (kt unrolled)

      // issue next phase's A-frags (hidden under this phase's ds_read+MFMA)
      if (ph + 1 < NPH){
        int bt2 = (kt == NT-1) ? bt+1 : bt;
        int kt2 = (kt == NT-1) ? 0    : kt+1;
        if (cb == 0) { ALOAD(1, bt2, kt2) }
        else         { ALOAD(0, bt2, kt2) }
      }
      if (kt == 0){                              // gates for this bt (used at epi)
        gv[0] = *(const float4*)(gtrow + bt*BTR + wm*32 + lk*4);
        gv[1] = *(const float4*)(gtrow + bt*BTR + wm*32 + 16 + lk*4);
      }

      #pragma unroll
      for (int kk = 0; kk < 2; ++kk){
        short8 b[4];
        #pragma unroll
        for (int fn = 0; fn < 4; ++fn)
          b[fn] = *(const short8*)(ldsc + kt*KTB + (boff[fn] ^ (unsigned)(kk*64)));
        #pragma unroll
        for (int fm = 0; fm < 2; ++fm)
          #pragma unroll
          for (int fn = 0; fn < 4; ++fn)
            acc[fm][fn] = __builtin_amdgcn_mfma_f32_16x16x32_bf16(
                areg[cb][kk][fm], b[fn], acc[fm][fn], 0, 0, 0);
      }

      if (kt == NT-1){
        #pragma unroll
        for (int fm = 0; fm < 2; ++fm){
          float gr[4] = {gv[fm].x, gv[fm].y, gv[fm].z, gv[fm].w};
          float sums[4];
          #pragma unroll
          for (int reg = 0; reg < 4; ++reg){
            float s = 0.f;
            #pragma unroll
            for (int fn = 0; fn < 4; ++fn)
              s += fmaxf(acc[fm][fn][reg] + bbv[fn], 0.f) * wsv[fn];
            sums[reg] = rowred16(s * gr[reg]);
          }
          if (lrow == 0){
            float4 o; o.x = sums[0]; o.y = sums[1]; o.z = sums[2]; o.w = sums[3];
            *(float4*)(prow + bt*BTR + wm*32 + fm*16 + lk*4) = o;
          }
        }
        #pragma unroll
        for (int i2 = 0; i2 < 2; ++i2)
          #pragma unroll
          for (int j2 = 0; j2 < 4; ++j2) acc[i2][j2] = zero;
      }
    }
  }
  #undef ALOAD
}

// ---------- 6.5 partial fold: out[b][n] = sum_k partg[k][n][b] + bs[n] ----------
template<int OUT_BF>
__global__ void k_mid(const float* __restrict__ partg, const float* __restrict__ bsv,
                      unsigned short* __restrict__ obf, float* __restrict__ of32){
  const int n = blockIdx.x;
  const int t = threadIdx.x;
  const float* p = partg + (size_t)n*4096 + t*16;
  const float bsn = bsv[n];
  #pragma unroll
  for (int i = 0; i < 4; ++i){
    float4 s0 = *(const float4*)(p + i*4);
    float4 s1 = *(const float4*)(p + 524288 + i*4);
    float4 s2 = *(const float4*)(p + 2*524288 + i*4);
    float4 s3 = *(const float4*)(p + 3*524288 + i*4);
    float v0 = ((s0.x + s1.x) + s2.x) + s3.x + bsn;
    float v1 = ((s0.y + s1.y) + s2.y) + s3.y + bsn;
    float v2 = ((s0.z + s1.z) + s2.z) + s3.z + bsn;
    float v3 = ((s0.w + s1.w) + s2.w) + s3.w + bsn;
    size_t b = (size_t)t*16 + i*4;
    if (OUT_BF){
      obf[(b+0)*128 + n] = f2bf(v0);
      obf[(b+1)*128 + n] = f2bf(v1);
      obf[(b+2)*128 + n] = f2bf(v2);
      obf[(b+3)*128 + n] = f2bf(v3);
    } else {
      of32[(b+0)*128 + n] = v0;
      of32[(b+1)*128 + n] = v1;
      of32[(b+2)*128 + n] = v2;
      of32[(b+3)*128 + n] = v3;
    }
  }
}

// ---------- 7. final projection: out = cur1 @ Wout.T + bout ----------
__global__ void k_final(const float* __restrict__ out1, const float* __restrict__ Wout,
                        const float* __restrict__ bout, float* __restrict__ out){
  int t = blockIdx.x*256 + threadIdx.x;
  int b = t >> 7, o = t & 127;
  const float4* cr = (const float4*)(out1 + (size_t)b*128);
  const float4* wr = (const float4*)(Wout + (size_t)o*128);
  float a = 0.f;
  #pragma unroll
  for (int i = 0; i < 32; ++i){
    float4 c = cr[i], w = wr[i];
    a += c.x*w.x + c.y*w.y + c.z*w.z + c.w*w.w;
  }
  out[t] = a + bout[o];
}

// ---------- launch ----------
extern "C" void kernel_launch(void* const* d_in, const int* in_sizes, int n_in,
                              void* d_out, int out_size, void* d_ws, size_t ws_size,
                              hipStream_t stream){
  const float* x    = (const float*)d_in[0];
  const float* ctx  = (const float*)d_in[1];
  const float* Wb0  = (const float*)d_in[2];
  const float* bb0  = (const float*)d_in[3];
  const float* Ws0  = (const float*)d_in[4];
  const float* bs0  = (const float*)d_in[5];
  const float* Wb1  = (const float*)d_in[6];
  const float* bb1  = (const float*)d_in[7];
  const float* Ws1  = (const float*)d_in[8];
  const float* bs1  = (const float*)d_in[9];
  const float* Wout = (const float*)d_in[10];
  const float* bout = (const float*)d_in[11];
  const float* h1w  = (const float*)d_in[12];
  const float* h1b  = (const float*)d_in[13];
  const float* h2w  = (const float*)d_in[14];
  const float* h2b  = (const float*)d_in[15];
  const float* h3w  = (const float*)d_in[16];
  const float* h3b  = (const float*)d_in[17];
  float* out = (float*)d_out;

  char* ws = (char*)d_ws;
  size_t o = 0;
  unsigned short* x_bf  = (unsigned short*)(ws + o); o += (size_t)4096*256*2;
  unsigned short* Wg_bf = (unsigned short*)(ws + o); o += (size_t)1024*256*2;
  float* bg     = (float*)(ws + o); o += 1024*4;
  float* GT     = (float*)(ws + o); o += (size_t)1024*4096*4;
  unsigned short* cur_bf = (unsigned short*)(ws + o); o += (size_t)4096*128*2;
  float* out1   = (float*)(ws + o); o += (size_t)4096*128*4;
  float* partg0 = (float*)(ws + o); o += (size_t)4*128*4096*4;   // 8 MB
  float* partg1 = (float*)(ws + o); o += (size_t)4*128*4096*4;   // 8 MB

  k_convert<<<1024, 256, 0, stream>>>(x, x_bf);
  k_gw<<<4112, 512, 0, stream>>>(ctx, h1w, h1b, h2w, h2b, h3w, h3b, Wg_bf, bg);
  k_gates<<<dim3(8, 16), 512, 0, stream>>>(Wg_bf, x_bf, bg, GT);
  k_layer<256, 0><<<256, 1024, 0, stream>>>(x_bf, Wb0, bb0, Ws0, GT, partg0);
  k_mid<1><<<128, 256, 0, stream>>>(partg0, bs0, cur_bf, nullptr);
  k_layer<128, 1><<<256, 1024, 0, stream>>>(cur_bf, Wb1, bb1, Ws1, GT, partg1);
  k_mid<0><<<128, 256, 0, stream>>>(partg1, bs1, nullptr, out1);
  k_final<<<2048, 256, 0, stream>>>(out1, Wout, bout, out);
}

// Round 14
// 628.314 us; speedup vs baseline: 1.0049x; 1.0049x over previous
//
#include <hip/hip_runtime.h>

// ---------- problem constants ----------
#define BB   4096
#define IN_  256
#define NN   128
#define NG   512
#define WS_  131072     // IN*NG
#define PER  131584     // WS_+NG
#define TP   263168     // 2*PER

typedef __attribute__((ext_vector_type(8))) short short8;
typedef __attribute__((ext_vector_type(4))) float f32x4;

__device__ __forceinline__ unsigned short f2bf(float f){
  unsigned u = __float_as_uint(f);
  return (unsigned short)((u + 0x7fffu + ((u >> 16) & 1u)) >> 16);
}

// sum over each 16-lane row via DPP (VALU pipe)
__device__ __forceinline__ float rowred16(float s){
  s += __int_as_float(__builtin_amdgcn_update_dpp(0, __float_as_int(s), 0xB1,  0xF, 0xF, true));
  s += __int_as_float(__builtin_amdgcn_update_dpp(0, __float_as_int(s), 0x4E,  0xF, 0xF, true));
  s += __int_as_float(__builtin_amdgcn_update_dpp(0, __float_as_int(s), 0x124, 0xF, 0xF, true));
  s += __int_as_float(__builtin_amdgcn_update_dpp(0, __float_as_int(s), 0x128, 0xF, 0xF, true));
  return s;
}

// ---------- 1. f32 -> bf16 convert: x only ----------
__global__ void k_convert(const float* __restrict__ x, unsigned short* __restrict__ xb){
  size_t i = ((size_t)blockIdx.x*256 + threadIdx.x)*4;
  float4 v = *(const float4*)(x + i);
  ushort4 o;
  o.x = f2bf(v.x); o.y = f2bf(v.y); o.z = f2bf(v.z); o.w = f2bf(v.w);
  *(ushort4*)(xb + i) = o;
}

// ---------- 2. hypernet MLP + gw matvec (merged) ----------
__global__ __launch_bounds__(512)
void k_gw(const float* __restrict__ ctx,
          const float* __restrict__ h1w, const float* __restrict__ h1b,
          const float* __restrict__ h2w, const float* __restrict__ h2b,
          const float* __restrict__ h3w, const float* __restrict__ h3b,
          unsigned short* __restrict__ Wg_bf, float* __restrict__ bg){
  __shared__ float s1[32];
  __shared__ float hv2[64];
  const int t = threadIdx.x;
  if (t < 32){
    float a = h1b[t];
    #pragma unroll 8
    for (int i = 0; i < 64; ++i) a += ctx[i]*h1w[t*64+i];
    s1[t] = fmaxf(a, 0.f);
  }
  __syncthreads();
  if (t < 64){
    float a = h2b[t];
    #pragma unroll 8
    for (int i = 0; i < 32; ++i) a += s1[i]*h2w[t*32+i];
    hv2[t] = fmaxf(a, 0.f);
  }
  __syncthreads();

  const int r = blockIdx.x*64 + (t >> 3);
  const int q = t & 7;
  const float4* row = (const float4*)(h3w + (size_t)r*64);
  float4 v0 = row[q*2], v1 = row[q*2+1];
  float4 h0 = *(const float4*)(hv2 + q*8), h1 = *(const float4*)(hv2 + q*8 + 4);
  float a = v0.x*h0.x + v0.y*h0.y + v0.z*h0.z + v0.w*h0.w
          + v1.x*h1.x + v1.y*h1.y + v1.z*h1.z + v1.w*h1.w;
  a += __shfl_xor(a, 1);
  a += __shfl_xor(a, 2);
  a += __shfl_xor(a, 4);
  if (q == 0){
    a += h3b[r];
    if (r < WS_)          Wg_bf[r] = f2bf(a);
    else if (r < PER)     bg[r - WS_] = a;
    else if (r < PER+WS_) Wg_bf[WS_ + (r - PER)] = f2bf(a);
    else                  bg[512 + (r - (PER+WS_))] = a;
  }
}

// ---------- 4. gates GEMM: G_T[m][b] = sigmoid(Wg[m]·x[b] + bg[m]) ----------
__global__ __launch_bounds__(512, 1)
void k_gates(const unsigned short* __restrict__ Wg_bf,
             const unsigned short* __restrict__ x_bf,
             const float* __restrict__ bg,
             float* __restrict__ GT){
  __shared__ __align__(16) unsigned short As[128*64];
  __shared__ __align__(16) unsigned short Bs[256*64];
  const int tid  = threadIdx.x;
  const int lane = tid & 63;
  const int wid  = tid >> 6;
  const int wm = wid >> 2, wn = wid & 3;
  const int lrow = lane & 15, lk = lane >> 4;
  const int m0 = blockIdx.x*128;
  const int b0 = blockIdx.y*256;

  f32x4 zero = {0.f,0.f,0.f,0.f};
  f32x4 acc[4][4];
  #pragma unroll
  for (int i=0;i<4;++i)
    #pragma unroll
    for (int j=0;j<4;++j) acc[i][j] = zero;

  for (int kt = 0; kt < 256/64; ++kt){
    __syncthreads();
    #pragma unroll
    for (int i = 0; i < 2; ++i){
      int c = tid + i*512;
      int row = c >> 3, k8 = c & 7;
      uint4 v = *(const uint4*)(Wg_bf + (size_t)(m0+row)*256 + kt*64 + k8*8);
      int idx = (row*64 + k8*8) ^ ((row & 7) << 3);
      *(uint4*)(&As[idx]) = v;
    }
    #pragma unroll
    for (int i = 0; i < 4; ++i){
      int c = tid + i*512;
      int row = c >> 3, k8 = c & 7;
      uint4 v = *(const uint4*)(x_bf + (size_t)(b0+row)*256 + kt*64 + k8*8);
      int idx = (row*64 + k8*8) ^ ((row & 7) << 3);
      *(uint4*)(&Bs[idx]) = v;
    }
    __syncthreads();
    #pragma unroll
    for (int kk = 0; kk < 2; ++kk){
      short8 a[4], b[4];
      #pragma unroll
      for (int fm = 0; fm < 4; ++fm){
        int m = wm*64 + fm*16 + lrow;
        int idx = (m*64 + kk*32 + lk*8) ^ ((m & 7) << 3);
        a[fm] = *(const short8*)(&As[idx]);
      }
      #pragma unroll
      for (int fn = 0; fn < 4; ++fn){
        int r = wn*64 + fn*16 + lrow;
        int idx = (r*64 + kk*32 + lk*8) ^ ((r & 7) << 3);
        b[fn] = *(const short8*)(&Bs[idx]);
      }
      #pragma unroll
      for (int fm = 0; fm < 4; ++fm)
        #pragma unroll
        for (int fn = 0; fn < 4; ++fn)
          acc[fm][fn] = __builtin_amdgcn_mfma_f32_16x16x32_bf16(a[fm], b[fn], acc[fm][fn], 0, 0, 0);
    }
  }
  #pragma unroll
  for (int fm = 0; fm < 4; ++fm){
    float4 bgv = *(const float4*)(bg + m0 + wm*64 + fm*16 + lk*4);
    float bga[4] = {bgv.x, bgv.y, bgv.z, bgv.w};
    #pragma unroll
    for (int reg = 0; reg < 4; ++reg){
      int m = m0 + wm*64 + fm*16 + lk*4 + reg;
      #pragma unroll
      for (int fn = 0; fn < 4; ++fn){
        int b = b0 + wn*64 + fn*16 + lrow;
        float z = acc[fm][fn][reg] + bga[reg];
        GT[(size_t)m*4096 + b] = 1.f/(1.f + __expf(-z));
      }
    }
  }
}

// ---------- 5/6. fused DANN layer (barrier-free; LDS padded to force 1 block/CU) ----------
// Same structure as R12/R13: LDS = resident Wb only (staged once from f32);
// A-frags stream global->VGPR double-buffered; no main-loop barriers.
// KEY FIX: the backend sets the VGPR budget from LDS-derived occupancy
// (512/wavesPerSIMD), ignoring launch_bounds upward. 64 KB LDS admitted
// 2 blocks/CU -> 8 waves/SIMD -> 64-VGPR budget -> catastrophic spill
// (R12/R13: 135 MB scratch writes). Padding LDS to 84 KB (> 160/2 KB)
// forces 1 block/CU -> 4 waves/SIMD -> 128-VGPR budget; kernel needs ~110.
template<int KIN, int LAYER>
__global__ __launch_bounds__(1024, 4)
void k_layer(const unsigned short* __restrict__ Abf,  // (4096, KIN) bf16
             const float* __restrict__ Wf32,          // (32768, KIN) f32
             const float* __restrict__ bb,
             const float* __restrict__ Ws,
             const float* __restrict__ GT,            // 1024 x 4096
             float* __restrict__ partg){              // [4][128][4096] f32
  constexpr int NT   = KIN/64;                   // 4 / 2
  constexpr int SC   = (LAYER==0) ? 128 : 256;   // resident Wb cols
  constexpr int WN   = SC/64;                    // 2 / 4
  constexpr int BTR  = (LAYER==0) ? 256 : 128;   // rows per bt
  constexpr int NBT  = 16;
  constexpr int NPH  = NBT*NT;
  constexpr unsigned KTB = SC*64*2;              // bytes per Wb kt-tile
  // 64 KB of Wb + 20 KB pad = 84 KB -> exactly 1 block/CU (160 KB pool)
  __shared__ __align__(16) unsigned short lds[SC*64*NT + 10240];

  const int tid  = threadIdx.x;                  // 0..1023
  const int lane = tid & 63;
  const int wid  = tid >> 6;                     // 0..15
  const int wn   = wid % WN, wm = wid / WN;
  const int lrow = lane & 15, lk = lane >> 4;

  const int id      = blockIdx.x;                // 0..255
  const int n       = id >> 1;
  const int sub     = id & 1;
  const int kgrp    = (LAYER==0) ? sub*2 + wn : wn;
  const int abase   = (LAYER==0) ? 0 : sub*2048;
  const int colbase = n*256 + ((LAYER==0) ? sub*128 : 0);

  f32x4 zero = {0.f,0.f,0.f,0.f};
  f32x4 acc[2][4];
  #pragma unroll
  for (int i=0;i<2;++i)
    #pragma unroll
    for (int jj=0;jj<4;++jj) acc[i][jj] = zero;

  // ---- prologue: Wb f32 -> bf16 swizzled LDS staging (4096 16B-chunks) ----
  {
    constexpr int CHPR = KIN/8;                  // 16B-chunks per Wb row
    float4 va[4], vb[4];
    #pragma unroll
    for (int j = 0; j < 4; ++j){
      int c = j*1024 + tid;
      int r = c / CHPR, q = c % CHPR;
      const float4* s = (const float4*)(Wf32 + (size_t)(colbase + r)*KIN + q*8);
      va[j] = s[0]; vb[j] = s[1];
    }
    #pragma unroll
    for (int j = 0; j < 4; ++j){
      int c = j*1024 + tid;
      int r = c / CHPR, q = c % CHPR;
      int kt = q >> 3, k8 = q & 7;
      short8 p;
      p[0] = (short)f2bf(va[j].x); p[1] = (short)f2bf(va[j].y);
      p[2] = (short)f2bf(va[j].z); p[3] = (short)f2bf(va[j].w);
      p[4] = (short)f2bf(vb[j].x); p[5] = (short)f2bf(vb[j].y);
      p[6] = (short)f2bf(vb[j].z); p[7] = (short)f2bf(vb[j].w);
      int dst = kt*SC*64 + ((r*64 + k8*8) ^ ((r&7)<<3));
      *(short8*)(&lds[dst]) = p;
    }
  }

  // per-lane A base: rows (abase + wm*32 + fm*16 + lrow), k-chunk lk*8
  const unsigned short* abp = Abf + (size_t)(abase + wm*32 + lrow)*KIN + lk*8;

  // A-frag loads (global -> VGPR, 4 x dwordx4), static buffer indices
  short8 areg[2][2][2];                          // [buf][kk][fm]
  #define ALOAD(BUF, BT, KT)                                                   \
    _Pragma("unroll")                                                          \
    for (int kk_ = 0; kk_ < 2; ++kk_)                                          \
      _Pragma("unroll")                                                        \
      for (int fm_ = 0; fm_ < 2; ++fm_)                                        \
        areg[BUF][kk_][fm_] = *(const short8*)(abp +                           \
            (size_t)((BT)*BTR + fm_*16)*KIN + (KT)*64 + kk_*32);

  ALOAD(0, 0, 0)
  __syncthreads();                               // publish Wb LDS (once)

  // block-constant epilogue params
  float bbv[4], wsv[4];
  #pragma unroll
  for (int fn = 0; fn < 4; ++fn){
    int cloc = ((LAYER==0) ? sub*128 : 0) + wn*64 + fn*16 + lrow;
    bbv[fn] = bb[n*256 + cloc];
    wsv[fn] = Ws[n*256 + cloc];
  }
  const float* gtrow = GT + (size_t)(LAYER*512 + n*4 + kgrp)*4096 + abase;
  float* prow = partg + (size_t)kgrp*524288 + (size_t)n*4096 + abase;

  unsigned boff[4];
  #pragma unroll
  for (int fn = 0; fn < 4; ++fn){
    int r = wn*64 + fn*16 + lrow;
    boff[fn] = 2u*((unsigned)((r*64 + lk*8) ^ ((r & 7) << 3)));
  }
  const char* ldsc = (const char*)lds;

  #pragma unroll 1
  for (int bt = 0; bt < NBT; ++bt){
    float4 gv[2];
    #pragma unroll
    for (int kt = 0; kt < NT; ++kt){
      const int ph = bt*NT + kt;
      const int cb = kt & 1;                     // compile-time (kt unrolled)

      // issue next phase's A-frags (hidden under this phase's ds_read+MFMA)
      if (ph + 1 < NPH){
        int bt2 = (kt == NT-1) ? bt+1 : bt;
        int kt2 = (kt == NT-1) ? 0    : kt+1;
        if (cb == 0) { ALOAD(1, bt2, kt2) }
        else         { ALOAD(0, bt2, kt2) }
      }
      if (kt == 0){                              // gates for this bt (used at epi)
        gv[0] = *(const float4*)(gtrow + bt*BTR + wm*32 + lk*4);
        gv[1] = *(const float4*)(gtrow + bt*BTR + wm*32 + 16 + lk*4);
      }

      #pragma unroll
      for (int kk = 0; kk < 2; ++kk){
        short8 b[4];
        #pragma unroll
        for (int fn = 0; fn < 4; ++fn)
          b[fn] = *(const short8*)(ldsc + kt*KTB + (boff[fn] ^ (unsigned)(kk*64)));
        #pragma unroll
        for (int fm = 0; fm < 2; ++fm)
          #pragma unroll
          for (int fn = 0; fn < 4; ++fn)
            acc[fm][fn] = __builtin_amdgcn_mfma_f32_16x16x32_bf16(
                areg[cb][kk][fm], b[fn], acc[fm][fn], 0, 0, 0);
      }

      if (kt == NT-1){
        #pragma unroll
        for (int fm = 0; fm < 2; ++fm){
          float gr[4] = {gv[fm].x, gv[fm].y, gv[fm].z, gv[fm].w};
          float sums[4];
          #pragma unroll
          for (int reg = 0; reg < 4; ++reg){
            float s = 0.f;
            #pragma unroll
            for (int fn = 0; fn < 4; ++fn)
              s += fmaxf(acc[fm][fn][reg] + bbv[fn], 0.f) * wsv[fn];
            sums[reg] = rowred16(s * gr[reg]);
          }
          if (lrow == 0){
            float4 o; o.x = sums[0]; o.y = sums[1]; o.z = sums[2]; o.w = sums[3];
            *(float4*)(prow + bt*BTR + wm*32 + fm*16 + lk*4) = o;
          }
        }
        #pragma unroll
        for (int i2 = 0; i2 < 2; ++i2)
          #pragma unroll
          for (int j2 = 0; j2 < 4; ++j2) acc[i2][j2] = zero;
      }
    }
  }
  #undef ALOAD
}

// ---------- 6.5 partial fold: out[b][n] = sum_k partg[k][n][b] + bs[n] ----------
template<int OUT_BF>
__global__ void k_mid(const float* __restrict__ partg, const float* __restrict__ bsv,
                      unsigned short* __restrict__ obf, float* __restrict__ of32){
  const int n = blockIdx.x;
  const int t = threadIdx.x;
  const float* p = partg + (size_t)n*4096 + t*16;
  const float bsn = bsv[n];
  #pragma unroll
  for (int i = 0; i < 4; ++i){
    float4 s0 = *(const float4*)(p + i*4);
    float4 s1 = *(const float4*)(p + 524288 + i*4);
    float4 s2 = *(const float4*)(p + 2*524288 + i*4);
    float4 s3 = *(const float4*)(p + 3*524288 + i*4);
    float v0 = ((s0.x + s1.x) + s2.x) + s3.x + bsn;
    float v1 = ((s0.y + s1.y) + s2.y) + s3.y + bsn;
    float v2 = ((s0.z + s1.z) + s2.z) + s3.z + bsn;
    float v3 = ((s0.w + s1.w) + s2.w) + s3.w + bsn;
    size_t b = (size_t)t*16 + i*4;
    if (OUT_BF){
      obf[(b+0)*128 + n] = f2bf(v0);
      obf[(b+1)*128 + n] = f2bf(v1);
      obf[(b+2)*128 + n] = f2bf(v2);
      obf[(b+3)*128 + n] = f2bf(v3);
    } else {
      of32[(b+0)*128 + n] = v0;
      of32[(b+1)*128 + n] = v1;
      of32[(b+2)*128 + n] = v2;
      of32[(b+3)*128 + n] = v3;
    }
  }
}

// ---------- 7. final projection: out = cur1 @ Wout.T + bout ----------
__global__ void k_final(const float* __restrict__ out1, const float* __restrict__ Wout,
                        const float* __restrict__ bout, float* __restrict__ out){
  int t = blockIdx.x*256 + threadIdx.x;
  int b = t >> 7, o = t & 127;
  const float4* cr = (const float4*)(out1 + (size_t)b*128);
  const float4* wr = (const float4*)(Wout + (size_t)o*128);
  float a = 0.f;
  #pragma unroll
  for (int i = 0; i < 32; ++i){
    float4 c = cr[i], w = wr[i];
    a += c.x*w.x + c.y*w.y + c.z*w.z + c.w*w.w;
  }
  out[t] = a + bout[o];
}

// ---------- launch ----------
extern "C" void kernel_launch(void* const* d_in, const int* in_sizes, int n_in,
                              void* d_out, int out_size, void* d_ws, size_t ws_size,
                              hipStream_t stream){
  const float* x    = (const float*)d_in[0];
  const float* ctx  = (const float*)d_in[1];
  const float* Wb0  = (const float*)d_in[2];
  const float* bb0  = (const float*)d_in[3];
  const float* Ws0  = (const float*)d_in[4];
  const float* bs0  = (const float*)d_in[5];
  const float* Wb1  = (const float*)d_in[6];
  const float* bb1  = (const float*)d_in[7];
  const float* Ws1  = (const float*)d_in[8];
  const float* bs1  = (const float*)d_in[9];
  const float* Wout = (const float*)d_in[10];
  const float* bout = (const float*)d_in[11];
  const float* h1w  = (const float*)d_in[12];
  const float* h1b  = (const float*)d_in[13];
  const float* h2w  = (const float*)d_in[14];
  const float* h2b  = (const float*)d_in[15];
  const float* h3w  = (const float*)d_in[16];
  const float* h3b  = (const float*)d_in[17];
  float* out = (float*)d_out;

  char* ws = (char*)d_ws;
  size_t o = 0;
  unsigned short* x_bf  = (unsigned short*)(ws + o); o += (size_t)4096*256*2;
  unsigned short* Wg_bf = (unsigned short*)(ws + o); o += (size_t)1024*256*2;
  float* bg     = (float*)(ws + o); o += 1024*4;
  float* GT     = (float*)(ws + o); o += (size_t)1024*4096*4;
  unsigned short* cur_bf = (unsigned short*)(ws + o); o += (size_t)4096*128*2;
  float* out1   = (float*)(ws + o); o += (size_t)4096*128*4;
  float* partg0 = (float*)(ws + o); o += (size_t)4*128*4096*4;   // 8 MB
  float* partg1 = (float*)(ws + o); o += (size_t)4*128*4096*4;   // 8 MB

  k_convert<<<1024, 256, 0, stream>>>(x, x_bf);
  k_gw<<<4112, 512, 0, stream>>>(ctx, h1w, h1b, h2w, h2b, h3w, h3b, Wg_bf, bg);
  k_gates<<<dim3(8, 16), 512, 0, stream>>>(Wg_bf, x_bf, bg, GT);
  k_layer<256, 0><<<256, 1024, 0, stream>>>(x_bf, Wb0, bb0, Ws0, GT, partg0);
  k_mid<1><<<128, 256, 0, stream>>>(partg0, bs0, cur_bf, nullptr);
  k_layer<128, 1><<<256, 1024, 0, stream>>>(cur_bf, Wb1, bb1, Ws1, GT, partg1);
  k_mid<0><<<128, 256, 0, stream>>>(partg1, bs1, nullptr, out1);
  k_final<<<2048, 256, 0, stream>>>(out1, Wout, bout, out);
}

// Round 15
// 353.206 us; speedup vs baseline: 1.7876x; 1.7789x over previous
//
#include <hip/hip_runtime.h>

// ---------- problem constants ----------
#define BB   4096
#define IN_  256
#define NN   128
#define NG   512
#define WS_  131072     // IN*NG
#define PER  131584     // WS_+NG
#define TP   263168     // 2*PER

typedef __attribute__((ext_vector_type(8))) short short8;
typedef __attribute__((ext_vector_type(4))) float f32x4;

__device__ __forceinline__ unsigned short f2bf(float f){
  unsigned u = __float_as_uint(f);
  return (unsigned short)((u + 0x7fffu + ((u >> 16) & 1u)) >> 16);
}

// sum over each 16-lane row via DPP (VALU pipe)
__device__ __forceinline__ float rowred16(float s){
  s += __int_as_float(__builtin_amdgcn_update_dpp(0, __float_as_int(s), 0xB1,  0xF, 0xF, true));
  s += __int_as_float(__builtin_amdgcn_update_dpp(0, __float_as_int(s), 0x4E,  0xF, 0xF, true));
  s += __int_as_float(__builtin_amdgcn_update_dpp(0, __float_as_int(s), 0x124, 0xF, 0xF, true));
  s += __int_as_float(__builtin_amdgcn_update_dpp(0, __float_as_int(s), 0x128, 0xF, 0xF, true));
  return s;
}

// ---------- 1. f32 -> bf16 convert: x only ----------
__global__ void k_convert(const float* __restrict__ x, unsigned short* __restrict__ xb){
  size_t i = ((size_t)blockIdx.x*256 + threadIdx.x)*4;
  float4 v = *(const float4*)(x + i);
  ushort4 o;
  o.x = f2bf(v.x); o.y = f2bf(v.y); o.z = f2bf(v.z); o.w = f2bf(v.w);
  *(ushort4*)(xb + i) = o;
}

// ---------- 2. hypernet MLP + gw matvec (merged) ----------
__global__ __launch_bounds__(512)
void k_gw(const float* __restrict__ ctx,
          const float* __restrict__ h1w, const float* __restrict__ h1b,
          const float* __restrict__ h2w, const float* __restrict__ h2b,
          const float* __restrict__ h3w, const float* __restrict__ h3b,
          unsigned short* __restrict__ Wg_bf, float* __restrict__ bg){
  __shared__ float s1[32];
  __shared__ float hv2[64];
  const int t = threadIdx.x;
  if (t < 32){
    float a = h1b[t];
    #pragma unroll 8
    for (int i = 0; i < 64; ++i) a += ctx[i]*h1w[t*64+i];
    s1[t] = fmaxf(a, 0.f);
  }
  __syncthreads();
  if (t < 64){
    float a = h2b[t];
    #pragma unroll 8
    for (int i = 0; i < 32; ++i) a += s1[i]*h2w[t*32+i];
    hv2[t] = fmaxf(a, 0.f);
  }
  __syncthreads();

  const int r = blockIdx.x*64 + (t >> 3);
  const int q = t & 7;
  const float4* row = (const float4*)(h3w + (size_t)r*64);
  float4 v0 = row[q*2], v1 = row[q*2+1];
  float4 h0 = *(const float4*)(hv2 + q*8), h1 = *(const float4*)(hv2 + q*8 + 4);
  float a = v0.x*h0.x + v0.y*h0.y + v0.z*h0.z + v0.w*h0.w
          + v1.x*h1.x + v1.y*h1.y + v1.z*h1.z + v1.w*h1.w;
  a += __shfl_xor(a, 1);
  a += __shfl_xor(a, 2);
  a += __shfl_xor(a, 4);
  if (q == 0){
    a += h3b[r];
    if (r < WS_)          Wg_bf[r] = f2bf(a);
    else if (r < PER)     bg[r - WS_] = a;
    else if (r < PER+WS_) Wg_bf[WS_ + (r - PER)] = f2bf(a);
    else                  bg[512 + (r - (PER+WS_))] = a;
  }
}

// ---------- 4. gates GEMM: G_T[m][b] = sigmoid(Wg[m]·x[b] + bg[m]) ----------
__global__ __launch_bounds__(512, 1)
void k_gates(const unsigned short* __restrict__ Wg_bf,
             const unsigned short* __restrict__ x_bf,
             const float* __restrict__ bg,
             float* __restrict__ GT){
  __shared__ __align__(16) unsigned short As[128*64];
  __shared__ __align__(16) unsigned short Bs[256*64];
  const int tid  = threadIdx.x;
  const int lane = tid & 63;
  const int wid  = tid >> 6;
  const int wm = wid >> 2, wn = wid & 3;
  const int lrow = lane & 15, lk = lane >> 4;
  const int m0 = blockIdx.x*128;
  const int b0 = blockIdx.y*256;

  f32x4 zero = {0.f,0.f,0.f,0.f};
  f32x4 acc[4][4];
  #pragma unroll
  for (int i=0;i<4;++i)
    #pragma unroll
    for (int j=0;j<4;++j) acc[i][j] = zero;

  for (int kt = 0; kt < 256/64; ++kt){
    __syncthreads();
    #pragma unroll
    for (int i = 0; i < 2; ++i){
      int c = tid + i*512;
      int row = c >> 3, k8 = c & 7;
      uint4 v = *(const uint4*)(Wg_bf + (size_t)(m0+row)*256 + kt*64 + k8*8);
      int idx = (row*64 + k8*8) ^ ((row & 7) << 3);
      *(uint4*)(&As[idx]) = v;
    }
    #pragma unroll
    for (int i = 0; i < 4; ++i){
      int c = tid + i*512;
      int row = c >> 3, k8 = c & 7;
      uint4 v = *(const uint4*)(x_bf + (size_t)(b0+row)*256 + kt*64 + k8*8);
      int idx = (row*64 + k8*8) ^ ((row & 7) << 3);
      *(uint4*)(&Bs[idx]) = v;
    }
    __syncthreads();
    #pragma unroll
    for (int kk = 0; kk < 2; ++kk){
      short8 a[4], b[4];
      #pragma unroll
      for (int fm = 0; fm < 4; ++fm){
        int m = wm*64 + fm*16 + lrow;
        int idx = (m*64 + kk*32 + lk*8) ^ ((m & 7) << 3);
        a[fm] = *(const short8*)(&As[idx]);
      }
      #pragma unroll
      for (int fn = 0; fn < 4; ++fn){
        int r = wn*64 + fn*16 + lrow;
        int idx = (r*64 + kk*32 + lk*8) ^ ((r & 7) << 3);
        b[fn] = *(const short8*)(&Bs[idx]);
      }
      #pragma unroll
      for (int fm = 0; fm < 4; ++fm)
        #pragma unroll
        for (int fn = 0; fn < 4; ++fn)
          acc[fm][fn] = __builtin_amdgcn_mfma_f32_16x16x32_bf16(a[fm], b[fn], acc[fm][fn], 0, 0, 0);
    }
  }
  #pragma unroll
  for (int fm = 0; fm < 4; ++fm){
    float4 bgv = *(const float4*)(bg + m0 + wm*64 + fm*16 + lk*4);
    float bga[4] = {bgv.x, bgv.y, bgv.z, bgv.w};
    #pragma unroll
    for (int reg = 0; reg < 4; ++reg){
      int m = m0 + wm*64 + fm*16 + lk*4 + reg;
      #pragma unroll
      for (int fn = 0; fn < 4; ++fn){
        int b = b0 + wn*64 + fn*16 + lrow;
        float z = acc[fm][fn][reg] + bga[reg];
        GT[(size_t)m*4096 + b] = 1.f/(1.f + __expf(-z));
      }
    }
  }
}

// ---------- 5/6. fused DANN layer (barrier-free; 512-thread envelope) ----------
// Structure = R12 (LDS holds ONLY resident Wb, staged once from f32; A-frags
// stream global->VGPR double-buffered; no main-loop barriers) but in the
// register envelope this toolchain actually honors: 512-thread blocks +
// launch_bounds(512,1) + LDS>80 KB -> 1 block/CU, 2 waves/SIMD, 256-reg
// unified budget (R6/R8/R10 precedent: 108-128 VGPR, no spill). 1024-thread
// blocks pinned VGPR=64 and spilled 135 MB (R12-R14).
// Per-wave tile 64x64: fm4 x fn4 x kk2 = 32 MFMA/phase; areg dbuf 64 regs,
// acc 64 AGPR. Phase/SIMD: MFMA 2x32x16 = 1024 cyc (bound); LDS B-reads only.
template<int KIN, int LAYER>
__global__ __launch_bounds__(512, 1)
void k_layer(const unsigned short* __restrict__ Abf,  // (4096, KIN) bf16
             const float* __restrict__ Wf32,          // (32768, KIN) f32
             const float* __restrict__ bb,
             const float* __restrict__ Ws,
             const float* __restrict__ GT,            // 1024 x 4096
             float* __restrict__ partg){              // [4][128][4096] f32
  constexpr int NT   = KIN/64;                   // 4 / 2
  constexpr int SC   = (LAYER==0) ? 128 : 256;   // resident Wb cols
  constexpr int WN   = SC/64;                    // 2 / 4
  constexpr int BTR  = (LAYER==0) ? 256 : 128;   // rows/bt = (8/WN)*64
  constexpr int NBT  = 16;
  constexpr int NPH  = NBT*NT;
  constexpr unsigned KTB = SC*64*2;              // bytes per Wb kt-tile
  // Wb 64 KB + 20 KB pad = 84 KB -> exactly 1 block/CU (160 KB pool)
  __shared__ __align__(16) unsigned short lds[SC*64*NT + 10240];

  const int tid  = threadIdx.x;                  // 0..511
  const int lane = tid & 63;
  const int wid  = tid >> 6;                     // 0..7
  const int wn   = wid % WN, wm = wid / WN;      // L0: wm 0..3; L1: wm 0..1
  const int lrow = lane & 15, lk = lane >> 4;

  const int id      = blockIdx.x;                // 0..255
  const int n       = id >> 1;
  const int sub     = id & 1;
  const int kgrp    = (LAYER==0) ? sub*2 + wn : wn;
  const int abase   = (LAYER==0) ? 0 : sub*2048;
  const int colbase = n*256 + ((LAYER==0) ? sub*128 : 0);

  f32x4 zero = {0.f,0.f,0.f,0.f};
  f32x4 acc[4][4];
  #pragma unroll
  for (int i=0;i<4;++i)
    #pragma unroll
    for (int jj=0;jj<4;++jj) acc[i][jj] = zero;

  // ---- prologue: Wb f32 -> bf16 swizzled LDS staging (4096 32B-chunks) ----
  {
    constexpr int CHPR = KIN/8;                  // 16B-pair chunks per Wb row
    #pragma unroll
    for (int half = 0; half < 2; ++half){
      float4 va[4], vb[4];
      #pragma unroll
      for (int j = 0; j < 4; ++j){
        int c = (half*4 + j)*512 + tid;
        int r = c / CHPR, q = c % CHPR;
        const float4* s = (const float4*)(Wf32 + (size_t)(colbase + r)*KIN + q*8);
        va[j] = s[0]; vb[j] = s[1];
      }
      #pragma unroll
      for (int j = 0; j < 4; ++j){
        int c = (half*4 + j)*512 + tid;
        int r = c / CHPR, q = c % CHPR;
        int kt = q >> 3, k8 = q & 7;
        short8 p;
        p[0] = (short)f2bf(va[j].x); p[1] = (short)f2bf(va[j].y);
        p[2] = (short)f2bf(va[j].z); p[3] = (short)f2bf(va[j].w);
        p[4] = (short)f2bf(vb[j].x); p[5] = (short)f2bf(vb[j].y);
        p[6] = (short)f2bf(vb[j].z); p[7] = (short)f2bf(vb[j].w);
        int dst = kt*SC*64 + ((r*64 + k8*8) ^ ((r&7)<<3));
        *(short8*)(&lds[dst]) = p;
      }
    }
  }

  // per-lane A base: rows (abase + wm*64 + fm*16 + lrow), k-chunk lk*8
  const unsigned short* abp = Abf + (size_t)(abase + wm*64 + lrow)*KIN + lk*8;

  // A-frag loads (global -> VGPR, 8 x dwordx4), static buffer indices
  short8 areg[2][2][4];                          // [buf][kk][fm]
  #define ALOAD(BUF, BT, KT)                                                   \
    _Pragma("unroll")                                                          \
    for (int kk_ = 0; kk_ < 2; ++kk_)                                          \
      _Pragma("unroll")                                                        \
      for (int fm_ = 0; fm_ < 4; ++fm_)                                        \
        areg[BUF][kk_][fm_] = *(const short8*)(abp +                           \
            (size_t)((BT)*BTR + fm_*16)*KIN + (KT)*64 + kk_*32);

  ALOAD(0, 0, 0)
  __syncthreads();                               // publish Wb LDS (once)

  // block-constant epilogue params
  float bbv[4], wsv[4];
  #pragma unroll
  for (int fn = 0; fn < 4; ++fn){
    int cloc = ((LAYER==0) ? sub*128 : 0) + wn*64 + fn*16 + lrow;
    bbv[fn] = bb[n*256 + cloc];
    wsv[fn] = Ws[n*256 + cloc];
  }
  const float* gtrow = GT + (size_t)(LAYER*512 + n*4 + kgrp)*4096 + abase;
  float* prow = partg + (size_t)kgrp*524288 + (size_t)n*4096 + abase;

  unsigned boff[4];
  #pragma unroll
  for (int fn = 0; fn < 4; ++fn){
    int r = wn*64 + fn*16 + lrow;
    boff[fn] = 2u*((unsigned)((r*64 + lk*8) ^ ((r & 7) << 3)));
  }
  const char* ldsc = (const char*)lds;

  #pragma unroll 1
  for (int bt = 0; bt < NBT; ++bt){
    float4 gv[4];
    #pragma unroll
    for (int kt = 0; kt < NT; ++kt){
      const int ph = bt*NT + kt;
      const int cb = kt & 1;                     // compile-time (kt unrolled)

      // issue next phase's A-frags (hidden under this phase's ds_read+MFMA)
      if (ph + 1 < NPH){
        int bt2 = (kt == NT-1) ? bt+1 : bt;
        int kt2 = (kt == NT-1) ? 0    : kt+1;
        if (cb == 0) { ALOAD(1, bt2, kt2) }
        else         { ALOAD(0, bt2, kt2) }
      }
      if (kt == 0){                              // gates for this bt (used at epi)
        #pragma unroll
        for (int fm = 0; fm < 4; ++fm)
          gv[fm] = *(const float4*)(gtrow + bt*BTR + wm*64 + fm*16 + lk*4);
      }

      #pragma unroll
      for (int kk = 0; kk < 2; ++kk){
        short8 b[4];
        #pragma unroll
        for (int fn = 0; fn < 4; ++fn)
          b[fn] = *(const short8*)(ldsc + kt*KTB + (boff[fn] ^ (unsigned)(kk*64)));
        #pragma unroll
        for (int fm = 0; fm < 4; ++fm)
          #pragma unroll
          for (int fn = 0; fn < 4; ++fn)
            acc[fm][fn] = __builtin_amdgcn_mfma_f32_16x16x32_bf16(
                areg[cb][kk][fm], b[fn], acc[fm][fn], 0, 0, 0);
      }

      if (kt == NT-1){
        #pragma unroll
        for (int fm = 0; fm < 4; ++fm){
          float gr[4] = {gv[fm].x, gv[fm].y, gv[fm].z, gv[fm].w};
          float sums[4];
          #pragma unroll
          for (int reg = 0; reg < 4; ++reg){
            float s = 0.f;
            #pragma unroll
            for (int fn = 0; fn < 4; ++fn)
              s += fmaxf(acc[fm][fn][reg] + bbv[fn], 0.f) * wsv[fn];
            sums[reg] = rowred16(s * gr[reg]);
          }
          if (lrow == 0){
            float4 o; o.x = sums[0]; o.y = sums[1]; o.z = sums[2]; o.w = sums[3];
            *(float4*)(prow + bt*BTR + wm*64 + fm*16 + lk*4) = o;
          }
        }
        #pragma unroll
        for (int i2 = 0; i2 < 4; ++i2)
          #pragma unroll
          for (int j2 = 0; j2 < 4; ++j2) acc[i2][j2] = zero;
      }
    }
  }
  #undef ALOAD
}

// ---------- 6.5 partial fold: out[b][n] = sum_k partg[k][n][b] + bs[n] ----------
template<int OUT_BF>
__global__ void k_mid(const float* __restrict__ partg, const float* __restrict__ bsv,
                      unsigned short* __restrict__ obf, float* __restrict__ of32){
  const int n = blockIdx.x;
  const int t = threadIdx.x;
  const float* p = partg + (size_t)n*4096 + t*16;
  const float bsn = bsv[n];
  #pragma unroll
  for (int i = 0; i < 4; ++i){
    float4 s0 = *(const float4*)(p + i*4);
    float4 s1 = *(const float4*)(p + 524288 + i*4);
    float4 s2 = *(const float4*)(p + 2*524288 + i*4);
    float4 s3 = *(const float4*)(p + 3*524288 + i*4);
    float v0 = ((s0.x + s1.x) + s2.x) + s3.x + bsn;
    float v1 = ((s0.y + s1.y) + s2.y) + s3.y + bsn;
    float v2 = ((s0.z + s1.z) + s2.z) + s3.z + bsn;
    float v3 = ((s0.w + s1.w) + s2.w) + s3.w + bsn;
    size_t b = (size_t)t*16 + i*4;
    if (OUT_BF){
      obf[(b+0)*128 + n] = f2bf(v0);
      obf[(b+1)*128 + n] = f2bf(v1);
      obf[(b+2)*128 + n] = f2bf(v2);
      obf[(b+3)*128 + n] = f2bf(v3);
    } else {
      of32[(b+0)*128 + n] = v0;
      of32[(b+1)*128 + n] = v1;
      of32[(b+2)*128 + n] = v2;
      of32[(b+3)*128 + n] = v3;
    }
  }
}

// ---------- 7. final projection: out = cur1 @ Wout.T + bout ----------
__global__ void k_final(const float* __restrict__ out1, const float* __restrict__ Wout,
                        const float* __restrict__ bout, float* __restrict__ out){
  int t = blockIdx.x*256 + threadIdx.x;
  int b = t >> 7, o = t & 127;
  const float4* cr = (const float4*)(out1 + (size_t)b*128);
  const float4* wr = (const float4*)(Wout + (size_t)o*128);
  float a = 0.f;
  #pragma unroll
  for (int i = 0; i < 32; ++i){
    float4 c = cr[i], w = wr[i];
    a += c.x*w.x + c.y*w.y + c.z*w.z + c.w*w.w;
  }
  out[t] = a + bout[o];
}

// ---------- launch ----------
extern "C" void kernel_launch(void* const* d_in, const int* in_sizes, int n_in,
                              void* d_out, int out_size, void* d_ws, size_t ws_size,
                              hipStream_t stream){
  const float* x    = (const float*)d_in[0];
  const float* ctx  = (const float*)d_in[1];
  const float* Wb0  = (const float*)d_in[2];
  const float* bb0  = (const float*)d_in[3];
  const float* Ws0  = (const float*)d_in[4];
  const float* bs0  = (const float*)d_in[5];
  const float* Wb1  = (const float*)d_in[6];
  const float* bb1  = (const float*)d_in[7];
  const float* Ws1  = (const float*)d_in[8];
  const float* bs1  = (const float*)d_in[9];
  const float* Wout = (const float*)d_in[10];
  const float* bout = (const float*)d_in[11];
  const float* h1w  = (const float*)d_in[12];
  const float* h1b  = (const float*)d_in[13];
  const float* h2w  = (const float*)d_in[14];
  const float* h2b  = (const float*)d_in[15];
  const float* h3w  = (const float*)d_in[16];
  const float* h3b  = (const float*)d_in[17];
  float* out = (float*)d_out;

  char* ws = (char*)d_ws;
  size_t o = 0;
  unsigned short* x_bf  = (unsigned short*)(ws + o); o += (size_t)4096*256*2;
  unsigned short* Wg_bf = (unsigned short*)(ws + o); o += (size_t)1024*256*2;
  float* bg     = (float*)(ws + o); o += 1024*4;
  float* GT     = (float*)(ws + o); o += (size_t)1024*4096*4;
  unsigned short* cur_bf = (unsigned short*)(ws + o); o += (size_t)4096*128*2;
  float* out1   = (float*)(ws + o); o += (size_t)4096*128*4;
  float* partg0 = (float*)(ws + o); o += (size_t)4*128*4096*4;   // 8 MB
  float* partg1 = (float*)(ws + o); o += (size_t)4*128*4096*4;   // 8 MB

  k_convert<<<1024, 256, 0, stream>>>(x, x_bf);
  k_gw<<<4112, 512, 0, stream>>>(ctx, h1w, h1b, h2w, h2b, h3w, h3b, Wg_bf, bg);
  k_gates<<<dim3(8, 16), 512, 0, stream>>>(Wg_bf, x_bf, bg, GT);
  k_layer<256, 0><<<256, 512, 0, stream>>>(x_bf, Wb0, bb0, Ws0, GT, partg0);
  k_mid<1><<<128, 256, 0, stream>>>(partg0, bs0, cur_bf, nullptr);
  k_layer<128, 1><<<256, 512, 0, stream>>>(cur_bf, Wb1, bb1, Ws1, GT, partg1);
  k_mid<0><<<128, 256, 0, stream>>>(partg1, bs1, nullptr, out1);
  k_final<<<2048, 256, 0, stream>>>(out1, Wout, bout, out);
}

// Round 16
// 308.726 us; speedup vs baseline: 2.0451x; 1.1441x over previous
//
#include <hip/hip_runtime.h>

// ---------- problem constants ----------
#define BB   4096
#define IN_  256
#define NN   128
#define NG   512
#define WS_  131072     // IN*NG
#define PER  131584     // WS_+NG
#define TP   263168     // 2*PER

typedef __attribute__((ext_vector_type(8))) short short8;
typedef __attribute__((ext_vector_type(4))) float f32x4;

__device__ __forceinline__ unsigned short f2bf(float f){
  unsigned u = __float_as_uint(f);
  return (unsigned short)((u + 0x7fffu + ((u >> 16) & 1u)) >> 16);
}

// sum over each 16-lane row via DPP (VALU pipe)
__device__ __forceinline__ float rowred16(float s){
  s += __int_as_float(__builtin_amdgcn_update_dpp(0, __float_as_int(s), 0xB1,  0xF, 0xF, true));
  s += __int_as_float(__builtin_amdgcn_update_dpp(0, __float_as_int(s), 0x4E,  0xF, 0xF, true));
  s += __int_as_float(__builtin_amdgcn_update_dpp(0, __float_as_int(s), 0x124, 0xF, 0xF, true));
  s += __int_as_float(__builtin_amdgcn_update_dpp(0, __float_as_int(s), 0x128, 0xF, 0xF, true));
  return s;
}

// ---------- 1. f32 -> bf16 convert: x only ----------
__global__ void k_convert(const float* __restrict__ x, unsigned short* __restrict__ xb){
  size_t i = ((size_t)blockIdx.x*256 + threadIdx.x)*4;
  float4 v = *(const float4*)(x + i);
  ushort4 o;
  o.x = f2bf(v.x); o.y = f2bf(v.y); o.z = f2bf(v.z); o.w = f2bf(v.w);
  *(ushort4*)(xb + i) = o;
}

// ---------- 2. hypernet MLP + gw matvec (merged) ----------
__global__ __launch_bounds__(512)
void k_gw(const float* __restrict__ ctx,
          const float* __restrict__ h1w, const float* __restrict__ h1b,
          const float* __restrict__ h2w, const float* __restrict__ h2b,
          const float* __restrict__ h3w, const float* __restrict__ h3b,
          unsigned short* __restrict__ Wg_bf, float* __restrict__ bg){
  __shared__ float s1[32];
  __shared__ float hv2[64];
  const int t = threadIdx.x;
  if (t < 32){
    float a = h1b[t];
    #pragma unroll 8
    for (int i = 0; i < 64; ++i) a += ctx[i]*h1w[t*64+i];
    s1[t] = fmaxf(a, 0.f);
  }
  __syncthreads();
  if (t < 64){
    float a = h2b[t];
    #pragma unroll 8
    for (int i = 0; i < 32; ++i) a += s1[i]*h2w[t*32+i];
    hv2[t] = fmaxf(a, 0.f);
  }
  __syncthreads();

  const int r = blockIdx.x*64 + (t >> 3);
  const int q = t & 7;
  const float4* row = (const float4*)(h3w + (size_t)r*64);
  float4 v0 = row[q*2], v1 = row[q*2+1];
  float4 h0 = *(const float4*)(hv2 + q*8), h1 = *(const float4*)(hv2 + q*8 + 4);
  float a = v0.x*h0.x + v0.y*h0.y + v0.z*h0.z + v0.w*h0.w
          + v1.x*h1.x + v1.y*h1.y + v1.z*h1.z + v1.w*h1.w;
  a += __shfl_xor(a, 1);
  a += __shfl_xor(a, 2);
  a += __shfl_xor(a, 4);
  if (q == 0){
    a += h3b[r];
    if (r < WS_)          Wg_bf[r] = f2bf(a);
    else if (r < PER)     bg[r - WS_] = a;
    else if (r < PER+WS_) Wg_bf[WS_ + (r - PER)] = f2bf(a);
    else                  bg[512 + (r - (PER+WS_))] = a;
  }
}

// ---------- 4. gates GEMM: G_T[m][b] = sigmoid(Wg[m]·x[b] + bg[m]) ----------
__global__ __launch_bounds__(512, 1)
void k_gates(const unsigned short* __restrict__ Wg_bf,
             const unsigned short* __restrict__ x_bf,
             const float* __restrict__ bg,
             float* __restrict__ GT){
  __shared__ __align__(16) unsigned short As[128*64];
  __shared__ __align__(16) unsigned short Bs[256*64];
  const int tid  = threadIdx.x;
  const int lane = tid & 63;
  const int wid  = tid >> 6;
  const int wm = wid >> 2, wn = wid & 3;
  const int lrow = lane & 15, lk = lane >> 4;
  const int m0 = blockIdx.x*128;
  const int b0 = blockIdx.y*256;

  f32x4 zero = {0.f,0.f,0.f,0.f};
  f32x4 acc[4][4];
  #pragma unroll
  for (int i=0;i<4;++i)
    #pragma unroll
    for (int j=0;j<4;++j) acc[i][j] = zero;

  for (int kt = 0; kt < 256/64; ++kt){
    __syncthreads();
    #pragma unroll
    for (int i = 0; i < 2; ++i){
      int c = tid + i*512;
      int row = c >> 3, k8 = c & 7;
      uint4 v = *(const uint4*)(Wg_bf + (size_t)(m0+row)*256 + kt*64 + k8*8);
      int idx = (row*64 + k8*8) ^ ((row & 7) << 3);
      *(uint4*)(&As[idx]) = v;
    }
    #pragma unroll
    for (int i = 0; i < 4; ++i){
      int c = tid + i*512;
      int row = c >> 3, k8 = c & 7;
      uint4 v = *(const uint4*)(x_bf + (size_t)(b0+row)*256 + kt*64 + k8*8);
      int idx = (row*64 + k8*8) ^ ((row & 7) << 3);
      *(uint4*)(&Bs[idx]) = v;
    }
    __syncthreads();
    #pragma unroll
    for (int kk = 0; kk < 2; ++kk){
      short8 a[4], b[4];
      #pragma unroll
      for (int fm = 0; fm < 4; ++fm){
        int m = wm*64 + fm*16 + lrow;
        int idx = (m*64 + kk*32 + lk*8) ^ ((m & 7) << 3);
        a[fm] = *(const short8*)(&As[idx]);
      }
      #pragma unroll
      for (int fn = 0; fn < 4; ++fn){
        int r = wn*64 + fn*16 + lrow;
        int idx = (r*64 + kk*32 + lk*8) ^ ((r & 7) << 3);
        b[fn] = *(const short8*)(&Bs[idx]);
      }
      #pragma unroll
      for (int fm = 0; fm < 4; ++fm)
        #pragma unroll
        for (int fn = 0; fn < 4; ++fn)
          acc[fm][fn] = __builtin_amdgcn_mfma_f32_16x16x32_bf16(a[fm], b[fn], acc[fm][fn], 0, 0, 0);
    }
  }
  #pragma unroll
  for (int fm = 0; fm < 4; ++fm){
    float4 bgv = *(const float4*)(bg + m0 + wm*64 + fm*16 + lk*4);
    float bga[4] = {bgv.x, bgv.y, bgv.z, bgv.w};
    #pragma unroll
    for (int reg = 0; reg < 4; ++reg){
      int m = m0 + wm*64 + fm*16 + lk*4 + reg;
      #pragma unroll
      for (int fn = 0; fn < 4; ++fn){
        int b = b0 + wn*64 + fn*16 + lrow;
        float z = acc[fm][fn][reg] + bga[reg];
        GT[(size_t)m*4096 + b] = 1.f/(1.f + __expf(-z));
      }
    }
  }
}

// ---------- 5/6. fused DANN layer (barrier-free, transient-register A) ----------
// B (Wb slice) resident in LDS (64 KB + 20 KB pad -> 1 block/CU), staged once
// from f32 with inline cvt; ONE __syncthreads after staging; no main-loop
// barriers or asm -- all loads compiler-visible.
// A-frags are PHASE-TRANSIENT (a[2][4], 16 regs, unroll-1 loops cap liveness);
// gates loaded INSIDE the epilogue (gv transient). Persistent arch regs ~40;
// peak ~75 << 128 cap; acc 64 in AGPRs (R6/R8/R10-proven envelope).
// Per-phase/CU: MFMA 1024 cyc, B ds_read 64 KB ~ 700 cyc, A L2-wait ~250
// (covered by 2nd wave/SIMD) -> ~1300-1500 cyc. L0: 64 phases, L1: 32.
template<int KIN, int LAYER>
__global__ __launch_bounds__(512, 1)
void k_layer(const unsigned short* __restrict__ Abf,  // (4096, KIN) bf16
             const float* __restrict__ Wf32,          // (32768, KIN) f32
             const float* __restrict__ bb,
             const float* __restrict__ Ws,
             const float* __restrict__ GT,            // 1024 x 4096
             float* __restrict__ partg){              // [4][128][4096] f32
  constexpr int NT  = KIN/64;                    // 4 / 2
  constexpr int SC  = (LAYER==0) ? 128 : 256;    // resident Wb cols
  constexpr int WN  = SC/64;                     // 2 / 4
  constexpr int WM  = 8/WN;                      // 4 / 2
  constexpr int BTR = WM*64;                     // 256 / 128
  constexpr int NBT = 16;
  constexpr unsigned KTB = SC*64*2;              // bytes per Wb kt-tile
  // Wb 64 KB + 20 KB pad = 84 KB -> exactly 1 block/CU
  __shared__ __align__(16) unsigned short lds[SC*64*NT + 10240];

  const int tid  = threadIdx.x;                  // 0..511
  const int lane = tid & 63;
  const int wid  = tid >> 6;                     // 0..7
  const int wn   = wid % WN, wm = wid / WN;
  const int lrow = lane & 15, lk = lane >> 4;

  const int id      = blockIdx.x;                // 0..255
  const int n       = id >> 1;
  const int sub     = id & 1;
  const int kgrp    = (LAYER==0) ? sub*2 + wn : wn;
  const int abase   = (LAYER==0) ? 0 : sub*2048;
  const int colbase = n*256 + ((LAYER==0) ? sub*128 : 0);

  f32x4 zero = {0.f,0.f,0.f,0.f};
  f32x4 acc[4][4];
  #pragma unroll
  for (int i=0;i<4;++i)
    #pragma unroll
    for (int jj=0;jj<4;++jj) acc[i][jj] = zero;

  // ---- prologue: Wb f32 -> bf16 swizzled LDS staging ----
  {
    constexpr int CHPR = KIN/8;                  // 16B-pair chunks per Wb row
    #pragma unroll
    for (int half = 0; half < 2; ++half){
      float4 va[4], vb[4];
      #pragma unroll
      for (int j = 0; j < 4; ++j){
        int c = (half*4 + j)*512 + tid;
        int r = c / CHPR, q = c % CHPR;
        const float4* s = (const float4*)(Wf32 + (size_t)(colbase + r)*KIN + q*8);
        va[j] = s[0]; vb[j] = s[1];
      }
      #pragma unroll
      for (int j = 0; j < 4; ++j){
        int c = (half*4 + j)*512 + tid;
        int r = c / CHPR, q = c % CHPR;
        int kt = q >> 3, k8 = q & 7;
        short8 p;
        p[0] = (short)f2bf(va[j].x); p[1] = (short)f2bf(va[j].y);
        p[2] = (short)f2bf(va[j].z); p[3] = (short)f2bf(va[j].w);
        p[4] = (short)f2bf(vb[j].x); p[5] = (short)f2bf(vb[j].y);
        p[6] = (short)f2bf(vb[j].z); p[7] = (short)f2bf(vb[j].w);
        int dst = kt*SC*64 + ((r*64 + k8*8) ^ ((r&7)<<3));
        *(short8*)(&lds[dst]) = p;
      }
    }
  }
  __syncthreads();                               // publish Wb LDS (only barrier)

  // block-constant epilogue params
  float bbv[4], wsv[4];
  #pragma unroll
  for (int fn = 0; fn < 4; ++fn){
    int cloc = ((LAYER==0) ? sub*128 : 0) + wn*64 + fn*16 + lrow;
    bbv[fn] = bb[n*256 + cloc];
    wsv[fn] = Ws[n*256 + cloc];
  }
  const float* gtrow = GT + (size_t)(LAYER*512 + n*4 + kgrp)*4096 + abase;
  float* prow = partg + (size_t)kgrp*524288 + (size_t)n*4096 + abase;

  // per-lane A base: rows (abase + wm*64 + fm*16 + lrow), k-chunk lk*8
  const unsigned short* abp = Abf + (size_t)(abase + wm*64 + lrow)*KIN + lk*8;

  unsigned boff[4];
  #pragma unroll
  for (int fn = 0; fn < 4; ++fn){
    int r = wn*64 + fn*16 + lrow;
    boff[fn] = 2u*((unsigned)((r*64 + lk*8) ^ ((r & 7) << 3)));
  }
  const char* ldsc = (const char*)lds;

  #pragma unroll 1
  for (int bt = 0; bt < NBT; ++bt){
    #pragma unroll 1
    for (int kt = 0; kt < NT; ++kt){
      // A fragments: global -> VGPR, phase-transient (8 x dwordx4)
      short8 a[2][4];
      #pragma unroll
      for (int kk = 0; kk < 2; ++kk)
        #pragma unroll
        for (int fm = 0; fm < 4; ++fm)
          a[kk][fm] = *(const short8*)(abp + (size_t)(bt*BTR + fm*16)*KIN
                                       + kt*64 + kk*32);
      // B from resident LDS + MFMA
      #pragma unroll
      for (int kk = 0; kk < 2; ++kk){
        short8 b[4];
        #pragma unroll
        for (int fn = 0; fn < 4; ++fn)
          b[fn] = *(const short8*)(ldsc + (unsigned)kt*KTB
                                   + (boff[fn] ^ (unsigned)(kk*64)));
        #pragma unroll
        for (int fm = 0; fm < 4; ++fm)
          #pragma unroll
          for (int fn = 0; fn < 4; ++fn)
            acc[fm][fn] = __builtin_amdgcn_mfma_f32_16x16x32_bf16(
                a[kk][fm], b[fn], acc[fm][fn], 0, 0, 0);
      }

      if (kt == NT-1){
        // epilogue: gates loaded here (transient), relu*Ws, DPP reduce, store
        #pragma unroll
        for (int fm = 0; fm < 4; ++fm){
          float4 g = *(const float4*)(gtrow + bt*BTR + wm*64 + fm*16 + lk*4);
          float gr[4] = {g.x, g.y, g.z, g.w};
          float sums[4];
          #pragma unroll
          for (int reg = 0; reg < 4; ++reg){
            float s = 0.f;
            #pragma unroll
            for (int fn = 0; fn < 4; ++fn)
              s += fmaxf(acc[fm][fn][reg] + bbv[fn], 0.f) * wsv[fn];
            sums[reg] = rowred16(s * gr[reg]);
          }
          if (lrow == 0){
            float4 o; o.x = sums[0]; o.y = sums[1]; o.z = sums[2]; o.w = sums[3];
            *(float4*)(prow + bt*BTR + wm*64 + fm*16 + lk*4) = o;
          }
        }
        #pragma unroll
        for (int i2 = 0; i2 < 4; ++i2)
          #pragma unroll
          for (int j2 = 0; j2 < 4; ++j2) acc[i2][j2] = zero;
      }
    }
  }
}

// ---------- 6.5 partial fold: out[b][n] = sum_k partg[k][n][b] + bs[n] ----------
template<int OUT_BF>
__global__ void k_mid(const float* __restrict__ partg, const float* __restrict__ bsv,
                      unsigned short* __restrict__ obf, float* __restrict__ of32){
  const int n = blockIdx.x;
  const int t = threadIdx.x;
  const float* p = partg + (size_t)n*4096 + t*16;
  const float bsn = bsv[n];
  #pragma unroll
  for (int i = 0; i < 4; ++i){
    float4 s0 = *(const float4*)(p + i*4);
    float4 s1 = *(const float4*)(p + 524288 + i*4);
    float4 s2 = *(const float4*)(p + 2*524288 + i*4);
    float4 s3 = *(const float4*)(p + 3*524288 + i*4);
    float v0 = ((s0.x + s1.x) + s2.x) + s3.x + bsn;
    float v1 = ((s0.y + s1.y) + s2.y) + s3.y + bsn;
    float v2 = ((s0.z + s1.z) + s2.z) + s3.z + bsn;
    float v3 = ((s0.w + s1.w) + s2.w) + s3.w + bsn;
    size_t b = (size_t)t*16 + i*4;
    if (OUT_BF){
      obf[(b+0)*128 + n] = f2bf(v0);
      obf[(b+1)*128 + n] = f2bf(v1);
      obf[(b+2)*128 + n] = f2bf(v2);
      obf[(b+3)*128 + n] = f2bf(v3);
    } else {
      of32[(b+0)*128 + n] = v0;
      of32[(b+1)*128 + n] = v1;
      of32[(b+2)*128 + n] = v2;
      of32[(b+3)*128 + n] = v3;
    }
  }
}

// ---------- 7. final projection: out = cur1 @ Wout.T + bout ----------
__global__ void k_final(const float* __restrict__ out1, const float* __restrict__ Wout,
                        const float* __restrict__ bout, float* __restrict__ out){
  int t = blockIdx.x*256 + threadIdx.x;
  int b = t >> 7, o = t & 127;
  const float4* cr = (const float4*)(out1 + (size_t)b*128);
  const float4* wr = (const float4*)(Wout + (size_t)o*128);
  float a = 0.f;
  #pragma unroll
  for (int i = 0; i < 32; ++i){
    float4 c = cr[i], w = wr[i];
    a += c.x*w.x + c.y*w.y + c.z*w.z + c.w*w.w;
  }
  out[t] = a + bout[o];
}

// ---------- launch ----------
extern "C" void kernel_launch(void* const* d_in, const int* in_sizes, int n_in,
                              void* d_out, int out_size, void* d_ws, size_t ws_size,
                              hipStream_t stream){
  const float* x    = (const float*)d_in[0];
  const float* ctx  = (const float*)d_in[1];
  const float* Wb0  = (const float*)d_in[2];
  const float* bb0  = (const float*)d_in[3];
  const float* Ws0  = (const float*)d_in[4];
  const float* bs0  = (const float*)d_in[5];
  const float* Wb1  = (const float*)d_in[6];
  const float* bb1  = (const float*)d_in[7];
  const float* Ws1  = (const float*)d_in[8];
  const float* bs1  = (const float*)d_in[9];
  const float* Wout = (const float*)d_in[10];
  const float* bout = (const float*)d_in[11];
  const float* h1w  = (const float*)d_in[12];
  const float* h1b  = (const float*)d_in[13];
  const float* h2w  = (const float*)d_in[14];
  const float* h2b  = (const float*)d_in[15];
  const float* h3w  = (const float*)d_in[16];
  const float* h3b  = (const float*)d_in[17];
  float* out = (float*)d_out;

  char* ws = (char*)d_ws;
  size_t o = 0;
  unsigned short* x_bf  = (unsigned short*)(ws + o); o += (size_t)4096*256*2;
  unsigned short* Wg_bf = (unsigned short*)(ws + o); o += (size_t)1024*256*2;
  float* bg     = (float*)(ws + o); o += 1024*4;
  float* GT     = (float*)(ws + o); o += (size_t)1024*4096*4;
  unsigned short* cur_bf = (unsigned short*)(ws + o); o += (size_t)4096*128*2;
  float* out1   = (float*)(ws + o); o += (size_t)4096*128*4;
  float* partg0 = (float*)(ws + o); o += (size_t)4*128*4096*4;   // 8 MB
  float* partg1 = (float*)(ws + o); o += (size_t)4*128*4096*4;   // 8 MB

  k_convert<<<1024, 256, 0, stream>>>(x, x_bf);
  k_gw<<<4112, 512, 0, stream>>>(ctx, h1w, h1b, h2w, h2b, h3w, h3b, Wg_bf, bg);
  k_gates<<<dim3(8, 16), 512, 0, stream>>>(Wg_bf, x_bf, bg, GT);
  k_layer<256, 0><<<256, 512, 0, stream>>>(x_bf, Wb0, bb0, Ws0, GT, partg0);
  k_mid<1><<<128, 256, 0, stream>>>(partg0, bs0, cur_bf, nullptr);
  k_layer<128, 1><<<256, 512, 0, stream>>>(cur_bf, Wb1, bb1, Ws1, GT, partg1);
  k_mid<0><<<128, 256, 0, stream>>>(partg1, bs1, nullptr, out1);
  k_final<<<2048, 256, 0, stream>>>(out1, Wout, bout, out);
}

// Round 17
// 215.834 us; speedup vs baseline: 2.9253x; 1.4304x over previous
//
#include <hip/hip_runtime.h>

// ---------- problem constants ----------
#define BB   4096
#define IN_  256
#define NN   128
#define NG   512
#define WS_  131072     // IN*NG
#define PER  131584     // WS_+NG
#define TP   263168     // 2*PER

typedef __attribute__((ext_vector_type(8))) short short8;
typedef __attribute__((ext_vector_type(4))) float f32x4;

#define VW(N) asm volatile("s_waitcnt vmcnt(" #N ")" ::: "memory")

__device__ __forceinline__ unsigned short f2bf(float f){
  unsigned u = __float_as_uint(f);
  return (unsigned short)((u + 0x7fffu + ((u >> 16) & 1u)) >> 16);
}

__device__ __forceinline__ void gload16(const void* g, void* l){
  __builtin_amdgcn_global_load_lds((const __attribute__((address_space(1))) void*)g,
                                   (__attribute__((address_space(3))) void*)l, 16, 0, 0);
}

// sum over each 16-lane row via DPP (VALU pipe; validated R9+)
__device__ __forceinline__ float rowred16(float s){
  s += __int_as_float(__builtin_amdgcn_update_dpp(0, __float_as_int(s), 0xB1,  0xF, 0xF, true));
  s += __int_as_float(__builtin_amdgcn_update_dpp(0, __float_as_int(s), 0x4E,  0xF, 0xF, true));
  s += __int_as_float(__builtin_amdgcn_update_dpp(0, __float_as_int(s), 0x124, 0xF, 0xF, true));
  s += __int_as_float(__builtin_amdgcn_update_dpp(0, __float_as_int(s), 0x128, 0xF, 0xF, true));
  return s;
}

// ---------- 1. f32 -> bf16 convert: x only ----------
__global__ void k_convert(const float* __restrict__ x, unsigned short* __restrict__ xb){
  size_t i = ((size_t)blockIdx.x*256 + threadIdx.x)*4;
  float4 v = *(const float4*)(x + i);
  ushort4 o;
  o.x = f2bf(v.x); o.y = f2bf(v.y); o.z = f2bf(v.z); o.w = f2bf(v.w);
  *(ushort4*)(xb + i) = o;
}

// ---------- 2. hypernet MLP + gw matvec (merged) ----------
__global__ __launch_bounds__(512)
void k_gw(const float* __restrict__ ctx,
          const float* __restrict__ h1w, const float* __restrict__ h1b,
          const float* __restrict__ h2w, const float* __restrict__ h2b,
          const float* __restrict__ h3w, const float* __restrict__ h3b,
          unsigned short* __restrict__ Wg_bf, float* __restrict__ bg){
  __shared__ float s1[32];
  __shared__ float hv2[64];
  const int t = threadIdx.x;
  if (t < 32){
    float a = h1b[t];
    #pragma unroll 8
    for (int i = 0; i < 64; ++i) a += ctx[i]*h1w[t*64+i];
    s1[t] = fmaxf(a, 0.f);
  }
  __syncthreads();
  if (t < 64){
    float a = h2b[t];
    #pragma unroll 8
    for (int i = 0; i < 32; ++i) a += s1[i]*h2w[t*32+i];
    hv2[t] = fmaxf(a, 0.f);
  }
  __syncthreads();

  const int r = blockIdx.x*64 + (t >> 3);
  const int q = t & 7;
  const float4* row = (const float4*)(h3w + (size_t)r*64);
  float4 v0 = row[q*2], v1 = row[q*2+1];
  float4 h0 = *(const float4*)(hv2 + q*8), h1 = *(const float4*)(hv2 + q*8 + 4);
  float a = v0.x*h0.x + v0.y*h0.y + v0.z*h0.z + v0.w*h0.w
          + v1.x*h1.x + v1.y*h1.y + v1.z*h1.z + v1.w*h1.w;
  a += __shfl_xor(a, 1);
  a += __shfl_xor(a, 2);
  a += __shfl_xor(a, 4);
  if (q == 0){
    a += h3b[r];
    if (r < WS_)          Wg_bf[r] = f2bf(a);
    else if (r < PER)     bg[r - WS_] = a;
    else if (r < PER+WS_) Wg_bf[WS_ + (r - PER)] = f2bf(a);
    else                  bg[512 + (r - (PER+WS_))] = a;
  }
}

// ---------- 4. gates GEMM: G_T[m][b] = sigmoid(Wg[m]·x[b] + bg[m]) ----------
__global__ __launch_bounds__(512, 1)
void k_gates(const unsigned short* __restrict__ Wg_bf,
             const unsigned short* __restrict__ x_bf,
             const float* __restrict__ bg,
             float* __restrict__ GT){
  __shared__ __align__(16) unsigned short As[128*64];
  __shared__ __align__(16) unsigned short Bs[256*64];
  const int tid  = threadIdx.x;
  const int lane = tid & 63;
  const int wid  = tid >> 6;
  const int wm = wid >> 2, wn = wid & 3;
  const int lrow = lane & 15, lk = lane >> 4;
  const int m0 = blockIdx.x*128;
  const int b0 = blockIdx.y*256;

  f32x4 zero = {0.f,0.f,0.f,0.f};
  f32x4 acc[4][4];
  #pragma unroll
  for (int i=0;i<4;++i)
    #pragma unroll
    for (int j=0;j<4;++j) acc[i][j] = zero;

  for (int kt = 0; kt < 256/64; ++kt){
    __syncthreads();
    #pragma unroll
    for (int i = 0; i < 2; ++i){
      int c = tid + i*512;
      int row = c >> 3, k8 = c & 7;
      uint4 v = *(const uint4*)(Wg_bf + (size_t)(m0+row)*256 + kt*64 + k8*8);
      int idx = (row*64 + k8*8) ^ ((row & 7) << 3);
      *(uint4*)(&As[idx]) = v;
    }
    #pragma unroll
    for (int i = 0; i < 4; ++i){
      int c = tid + i*512;
      int row = c >> 3, k8 = c & 7;
      uint4 v = *(const uint4*)(x_bf + (size_t)(b0+row)*256 + kt*64 + k8*8);
      int idx = (row*64 + k8*8) ^ ((row & 7) << 3);
      *(uint4*)(&Bs[idx]) = v;
    }
    __syncthreads();
    #pragma unroll
    for (int kk = 0; kk < 2; ++kk){
      short8 a[4], b[4];
      #pragma unroll
      for (int fm = 0; fm < 4; ++fm){
        int m = wm*64 + fm*16 + lrow;
        int idx = (m*64 + kk*32 + lk*8) ^ ((m & 7) << 3);
        a[fm] = *(const short8*)(&As[idx]);
      }
      #pragma unroll
      for (int fn = 0; fn < 4; ++fn){
        int r = wn*64 + fn*16 + lrow;
        int idx = (r*64 + kk*32 + lk*8) ^ ((r & 7) << 3);
        b[fn] = *(const short8*)(&Bs[idx]);
      }
      #pragma unroll
      for (int fm = 0; fm < 4; ++fm)
        #pragma unroll
        for (int fn = 0; fn < 4; ++fn)
          acc[fm][fn] = __builtin_amdgcn_mfma_f32_16x16x32_bf16(a[fm], b[fn], acc[fm][fn], 0, 0, 0);
    }
  }
  #pragma unroll
  for (int fm = 0; fm < 4; ++fm){
    float4 bgv = *(const float4*)(bg + m0 + wm*64 + fm*16 + lk*4);
    float bga[4] = {bgv.x, bgv.y, bgv.z, bgv.w};
    #pragma unroll
    for (int reg = 0; reg < 4; ++reg){
      int m = m0 + wm*64 + fm*16 + lk*4 + reg;
      #pragma unroll
      for (int fn = 0; fn < 4; ++fn){
        int b = b0 + wn*64 + fn*16 + lrow;
        float z = acc[fm][fn][reg] + bga[reg];
        GT[(size_t)m*4096 + b] = 1.f/(1.f + __expf(-z));
      }
    }
  }
}

// ---------- 5/6. fused DANN layer (fat wave tile 128x64, K=32 phases) ----------
// 512 thr, 8 waves; wave tile fm8 x fn4 -> LDS bytes/MFMA = 0.375 KB (half of
// R11's 0.75). acc 128 f32 -> AGPR pool; arch regs ~100 < 128 cap.
// LDS: Wb resident (64 KB, staged from f32, R11 layout/boff: 0 conflicts) +
// A dbuf 2 x BTR*32 bf16 (64/32 KB) -> 128/96 KB, 1 block/CU.
// A staged per K=32 phase via global_load_lds: linear dest, source pre-swizzled
// kc^((r>>1)&3); read aoff uses same XOR -> 8 dwords/bank uniform (conflict-free).
// Phase: [drain, barrier, {epi: G8 gates}, STAGE(ph+1), 8 a-reads + 4 b-reads,
// 32 MFMA, {epi: DPP reduce + 8 stores}]. Exact drains: bt-boundary VW(8)
// (E-stores younger than stage), mid-bt VW(0); ph0 covered by prologue sync.
template<int KIN, int LAYER>
__global__ __launch_bounds__(512, 1)
void k_layer(const unsigned short* __restrict__ Abf,  // (4096, KIN) bf16
             const float* __restrict__ Wf32,          // (32768, KIN) f32
             const float* __restrict__ bb,
             const float* __restrict__ Ws,
             const float* __restrict__ GT,            // 1024 x 4096
             float* __restrict__ partg){              // [4][128][4096] f32
  constexpr int NT   = KIN/64;                   // Wb K-64 tiles: 4 / 2
  constexpr int PPB  = KIN/32;                   // K=32 phases per bt: 8 / 4
  constexpr int SC   = (LAYER==0) ? 128 : 256;   // resident Wb cols
  constexpr int WN   = SC/64;                    // 2 / 4
  constexpr int WM   = 8/WN;                     // 4 / 2
  constexpr int BTR  = WM*128;                   // 512 / 256
  constexpr int NBT  = ((LAYER==0) ? 4096 : 2048)/BTR;   // 8 / 8
  constexpr int ABUFS = BTR*32;                  // shorts/buf: 16384 / 8192
  constexpr unsigned ABYTES = ABUFS*2;           // 32768 / 16384
  constexpr int WBOFFS = 2*ABUFS;                // shorts
  constexpr unsigned WBYTES = (unsigned)WBOFFS*2;
  constexpr unsigned KTB = SC*64*2;              // bytes per Wb kt-tile
  constexpr int SI   = (BTR*32*2)/8192;          // stage instrs/wave: 4 / 2
  __shared__ __align__(16) unsigned short lds[WBOFFS + SC*64*NT]; // 128/96 KB

  const int tid  = threadIdx.x;                  // 0..511
  const int lane = tid & 63;
  const int wid  = tid >> 6;                     // 0..7
  const int wn   = wid % WN, wm = wid / WN;
  const int lrow = lane & 15, lk = lane >> 4;

  const int id      = blockIdx.x;                // 0..255
  const int n       = id >> 1;
  const int sub     = id & 1;                    // khalf (L0) / bhalf (L1)
  const int kgrp    = (LAYER==0) ? sub*2 + wn : wn;
  const int abase   = (LAYER==0) ? 0 : sub*2048;
  const int colbase = n*256 + ((LAYER==0) ? sub*128 : 0);

  f32x4 zero = {0.f,0.f,0.f,0.f};
  f32x4 acc[8][4];                               // 128 f32 -> AGPR pool
  #pragma unroll
  for (int i=0;i<8;++i)
    #pragma unroll
    for (int jj=0;jj<4;++jj) acc[i][jj] = zero;

  // A-tile stage: BTR x 32 (K), linear LDS dest, source chunk pre-swizzled
  auto STAGE_A = [&](unsigned bufB, int bt2, int pk2){
    #pragma unroll
    for (int i = 0; i < SI; ++i){
      int c = i*512 + tid;                       // 16B-chunk index
      int r = c >> 2, kc = c & 3;
      int kg = kc ^ ((r >> 1) & 3);
      const unsigned short* s = Abf + (size_t)(abase + bt2*BTR + r)*KIN
                                + pk2*32 + kg*8;
      gload16(s, (char*)lds + bufB + (size_t)(i*512 + wid*64)*16);
    }
  };

  // ---- prologue: A(phase 0) async, then Wb f32->bf16 swizzled staging ----
  STAGE_A(0, 0, 0);
  asm volatile("" ::: "memory");
  {
    constexpr int CHPR = KIN/8;                  // 16B-pair chunks per Wb row
    #pragma unroll
    for (int half = 0; half < 2; ++half){
      float4 va[4], vb[4];
      #pragma unroll
      for (int j = 0; j < 4; ++j){
        int c = (half*4 + j)*512 + tid;
        int r = c / CHPR, q = c % CHPR;
        const float4* s = (const float4*)(Wf32 + (size_t)(colbase + r)*KIN + q*8);
        va[j] = s[0]; vb[j] = s[1];
      }
      #pragma unroll
      for (int j = 0; j < 4; ++j){
        int c = (half*4 + j)*512 + tid;
        int r = c / CHPR, q = c % CHPR;
        int kt = q >> 3, k8 = q & 7;
        short8 p;
        p[0] = (short)f2bf(va[j].x); p[1] = (short)f2bf(va[j].y);
        p[2] = (short)f2bf(va[j].z); p[3] = (short)f2bf(va[j].w);
        p[4] = (short)f2bf(vb[j].x); p[5] = (short)f2bf(vb[j].y);
        p[6] = (short)f2bf(vb[j].z); p[7] = (short)f2bf(vb[j].w);
        int dst = WBOFFS + kt*SC*64 + ((r*64 + k8*8) ^ ((r&7)<<3));
        *(short8*)(&lds[dst]) = p;
      }
    }
  }
  __syncthreads();                               // drains vmcnt+lgkm, publishes

  // block-constant epilogue params
  float bbv[4], wsv[4];
  #pragma unroll
  for (int fn = 0; fn < 4; ++fn){
    int cloc = ((LAYER==0) ? sub*128 : 0) + wn*64 + fn*16 + lrow;
    bbv[fn] = bb[n*256 + cloc];
    wsv[fn] = Ws[n*256 + cloc];
  }
  const float* gtrow = GT + (size_t)(LAYER*512 + n*4 + kgrp)*4096 + abase;
  float* prow = partg + (size_t)kgrp*524288 + (size_t)n*4096 + abase;

  // lane-invariant LDS byte offsets
  const int csw = lk ^ ((lrow >> 1) & 3);        // swizzled k-chunk
  unsigned aoff[8];
  #pragma unroll
  for (int fm = 0; fm < 8; ++fm){
    int row = wm*128 + fm*16 + lrow;
    aoff[fm] = (unsigned)(row*64 + csw*16);
  }
  unsigned boff[4];
  #pragma unroll
  for (int fn = 0; fn < 4; ++fn){
    int r = wn*64 + fn*16 + lrow;
    boff[fn] = 2u*((unsigned)((r*64 + lk*8) ^ ((r & 7) << 3)));
  }
  const char* ldsc = (const char*)lds;

  #pragma unroll 1
  for (int bt = 0; bt < NBT; ++bt){
    #pragma unroll
    for (int pk = 0; pk < PPB; ++pk){
      const unsigned curB = (unsigned)(pk & 1) * ABYTES;   // PPB even -> static
      const bool epi = (pk == PPB-1);

      // drain stage(ph): younger = 8 epi-stores at bt boundary, else none
      if (pk == 0){ if (bt > 0) VW(8); }
      else VW(0);
      __builtin_amdgcn_s_barrier();

      float4 gv[8];
      if (epi){                                  // gates BEFORE stage: their
        #pragma unroll                           // compiler-wait = vmcnt(SI)
        for (int fm = 0; fm < 8; ++fm)
          gv[fm] = *(const float4*)(gtrow + bt*BTR + wm*128 + fm*16 + lk*4);
      }
      if (!(epi && bt == NBT-1)){
        int bt2 = epi ? bt+1 : bt;
        int pk2 = epi ? 0    : pk+1;
        STAGE_A(((unsigned)((pk & 1) ^ 1))*ABYTES, bt2, pk2);
      }
      asm volatile("" ::: "memory");

      // 8 a-reads + 4 b-reads + 32 MFMA
      short8 a[8], b[4];
      #pragma unroll
      for (int fm = 0; fm < 8; ++fm)
        a[fm] = *(const short8*)(ldsc + curB + aoff[fm]);
      #pragma unroll
      for (int fn = 0; fn < 4; ++fn)
        b[fn] = *(const short8*)(ldsc + WBYTES + (unsigned)(pk>>1)*KTB
                                 + (boff[fn] ^ (unsigned)((pk & 1)*64)));
      #pragma unroll
      for (int fm = 0; fm < 8; ++fm)
        #pragma unroll
        for (int fn = 0; fn < 4; ++fn)
          acc[fm][fn] = __builtin_amdgcn_mfma_f32_16x16x32_bf16(
              a[fm], b[fn], acc[fm][fn], 0, 0, 0);

      if (epi){
        #pragma unroll
        for (int fm = 0; fm < 8; ++fm){
          float gr[4] = {gv[fm].x, gv[fm].y, gv[fm].z, gv[fm].w};
          float sums[4];
          #pragma unroll
          for (int reg = 0; reg < 4; ++reg){
            float s = 0.f;
            #pragma unroll
            for (int fn = 0; fn < 4; ++fn)
              s += fmaxf(acc[fm][fn][reg] + bbv[fn], 0.f) * wsv[fn];
            sums[reg] = rowred16(s * gr[reg]);
          }
          if (lrow == 0){
            float4 o; o.x = sums[0]; o.y = sums[1]; o.z = sums[2]; o.w = sums[3];
            *(float4*)(prow + bt*BTR + wm*128 + fm*16 + lk*4) = o;
          }
        }
        #pragma unroll
        for (int i2 = 0; i2 < 8; ++i2)
          #pragma unroll
          for (int j2 = 0; j2 < 4; ++j2) acc[i2][j2] = zero;
      }
    }
  }
}

// ---------- 6.5 partial fold: out[b][n] = sum_k partg[k][n][b] + bs[n] ----------
template<int OUT_BF>
__global__ void k_mid(const float* __restrict__ partg, const float* __restrict__ bsv,
                      unsigned short* __restrict__ obf, float* __restrict__ of32){
  const int n = blockIdx.x;
  const int t = threadIdx.x;
  const float* p = partg + (size_t)n*4096 + t*16;
  const float bsn = bsv[n];
  #pragma unroll
  for (int i = 0; i < 4; ++i){
    float4 s0 = *(const float4*)(p + i*4);
    float4 s1 = *(const float4*)(p + 524288 + i*4);
    float4 s2 = *(const float4*)(p + 2*524288 + i*4);
    float4 s3 = *(const float4*)(p + 3*524288 + i*4);
    float v0 = ((s0.x + s1.x) + s2.x) + s3.x + bsn;
    float v1 = ((s0.y + s1.y) + s2.y) + s3.y + bsn;
    float v2 = ((s0.z + s1.z) + s2.z) + s3.z + bsn;
    float v3 = ((s0.w + s1.w) + s2.w) + s3.w + bsn;
    size_t b = (size_t)t*16 + i*4;
    if (OUT_BF){
      obf[(b+0)*128 + n] = f2bf(v0);
      obf[(b+1)*128 + n] = f2bf(v1);
      obf[(b+2)*128 + n] = f2bf(v2);
      obf[(b+3)*128 + n] = f2bf(v3);
    } else {
      of32[(b+0)*128 + n] = v0;
      of32[(b+1)*128 + n] = v1;
      of32[(b+2)*128 + n] = v2;
      of32[(b+3)*128 + n] = v3;
    }
  }
}

// ---------- 7. final projection: out = cur1 @ Wout.T + bout ----------
__global__ void k_final(const float* __restrict__ out1, const float* __restrict__ Wout,
                        const float* __restrict__ bout, float* __restrict__ out){
  int t = blockIdx.x*256 + threadIdx.x;
  int b = t >> 7, o = t & 127;
  const float4* cr = (const float4*)(out1 + (size_t)b*128);
  const float4* wr = (const float4*)(Wout + (size_t)o*128);
  float a = 0.f;
  #pragma unroll
  for (int i = 0; i < 32; ++i){
    float4 c = cr[i], w = wr[i];
    a += c.x*w.x + c.y*w.y + c.z*w.z + c.w*w.w;
  }
  out[t] = a + bout[o];
}

// ---------- launch ----------
extern "C" void kernel_launch(void* const* d_in, const int* in_sizes, int n_in,
                              void* d_out, int out_size, void* d_ws, size_t ws_size,
                              hipStream_t stream){
  const float* x    = (const float*)d_in[0];
  const float* ctx  = (const float*)d_in[1];
  const float* Wb0  = (const float*)d_in[2];
  const float* bb0  = (const float*)d_in[3];
  const float* Ws0  = (const float*)d_in[4];
  const float* bs0  = (const float*)d_in[5];
  const float* Wb1  = (const float*)d_in[6];
  const float* bb1  = (const float*)d_in[7];
  const float* Ws1  = (const float*)d_in[8];
  const float* bs1  = (const float*)d_in[9];
  const float* Wout = (const float*)d_in[10];
  const float* bout = (const float*)d_in[11];
  const float* h1w  = (const float*)d_in[12];
  const float* h1b  = (const float*)d_in[13];
  const float* h2w  = (const float*)d_in[14];
  const float* h2b  = (const float*)d_in[15];
  const float* h3w  = (const float*)d_in[16];
  const float* h3b  = (const float*)d_in[17];
  float* out = (float*)d_out;

  char* ws = (char*)d_ws;
  size_t o = 0;
  unsigned short* x_bf  = (unsigned short*)(ws + o); o += (size_t)4096*256*2;
  unsigned short* Wg_bf = (unsigned short*)(ws + o); o += (size_t)1024*256*2;
  float* bg     = (float*)(ws + o); o += 1024*4;
  float* GT     = (float*)(ws + o); o += (size_t)1024*4096*4;
  unsigned short* cur_bf = (unsigned short*)(ws + o); o += (size_t)4096*128*2;
  float* out1   = (float*)(ws + o); o += (size_t)4096*128*4;
  float* partg0 = (float*)(ws + o); o += (size_t)4*128*4096*4;   // 8 MB
  float* partg1 = (float*)(ws + o); o += (size_t)4*128*4096*4;   // 8 MB

  k_convert<<<1024, 256, 0, stream>>>(x, x_bf);
  k_gw<<<4112, 512, 0, stream>>>(ctx, h1w, h1b, h2w, h2b, h3w, h3b, Wg_bf, bg);
  k_gates<<<dim3(8, 16), 512, 0, stream>>>(Wg_bf, x_bf, bg, GT);
  k_layer<256, 0><<<256, 512, 0, stream>>>(x_bf, Wb0, bb0, Ws0, GT, partg0);
  k_mid<1><<<128, 256, 0, stream>>>(partg0, bs0, cur_bf, nullptr);
  k_layer<128, 1><<<256, 512, 0, stream>>>(cur_bf, Wb1, bb1, Ws1, GT, partg1);
  k_mid<0><<<128, 256, 0, stream>>>(partg1, bs1, nullptr, out1);
  k_final<<<2048, 256, 0, stream>>>(out1, Wout, bout, out);
}